// Round 1
// baseline (374.991 us; speedup 1.0000x reference)
//
#include <hip/hip_runtime.h>
#include <math.h>

#define HID 512
#define NSEQ 256
#define BSZ 32
#define ROWS (BSZ*NSEQ)   // 8192

// ---------------- Kernel 1: proj GEMM: h = concat(columns,logits) @ Wp + bp ----------
// M=8192, K=514, N=512. BM=64,BN=64,BK=16, 256 thr, 4x4/thread.
__global__ __launch_bounds__(256) void proj_gemm(const float* __restrict__ cols,
    const float* __restrict__ logits, const float* __restrict__ Wp,
    const float* __restrict__ bp, float* __restrict__ hout)
{
    __shared__ float As[16][68];  // transposed: As[kk][row]
    __shared__ float Bs[16][68];
    int bx = blockIdx.x;          // col tile (8)
    int by = blockIdx.y;          // row tile (128)
    int tid = threadIdx.x;
    int tx = tid & 15, ty = tid >> 4;
    int row0 = by*64, col0 = bx*64;
    float acc[4][4] = {};
    for (int kt = 0; kt < 33; ++kt) {
        int k0 = kt*16;
        #pragma unroll
        for (int i = 0; i < 4; ++i) {
            int e = tid + i*256;
            int r = e >> 4, kk = e & 15;
            int k = k0 + kk;
            int row = row0 + r;
            float v = 0.f;
            if (k < 512) v = cols[row*512 + k];
            else if (k < 514) v = logits[row*2 + (k-512)];
            As[kk][r] = v;
        }
        #pragma unroll
        for (int i = 0; i < 4; ++i) {
            int e = tid + i*256;
            int kk = e >> 6, c = e & 63;
            int k = k0 + kk;
            float v = 0.f;
            if (k < 514) v = Wp[k*512 + col0 + c];
            Bs[kk][c] = v;
        }
        __syncthreads();
        #pragma unroll
        for (int kk = 0; kk < 16; ++kk) {
            float a[4], b[4];
            *(float4*)a = *(float4*)&As[kk][ty*4];
            *(float4*)b = *(float4*)&Bs[kk][tx*4];
            #pragma unroll
            for (int i = 0; i < 4; ++i)
                #pragma unroll
                for (int j = 0; j < 4; ++j)
                    acc[i][j] += a[i]*b[j];
        }
        __syncthreads();
    }
    #pragma unroll
    for (int i = 0; i < 4; ++i) {
        int row = row0 + ty*4 + i;
        float o[4];
        #pragma unroll
        for (int j = 0; j < 4; ++j)
            o[j] = acc[i][j] + bp[col0 + tx*4 + j];
        *(float4*)&hout[row*512 + col0 + tx*4] = *(float4*)o;
    }
}

// ---------------- Kernel 2: LayerNorm + exact GELU, in-place ----------------
__global__ __launch_bounds__(256) void ln_gelu(float* __restrict__ h,
    const float* __restrict__ g, const float* __restrict__ bb)
{
    int row = blockIdx.x;
    int tid = threadIdx.x;
    float v0 = h[row*512 + tid];
    float v1 = h[row*512 + 256 + tid];
    __shared__ float red[4];
    int wid = tid >> 6, lane = tid & 63;

    float s = v0 + v1;
    #pragma unroll
    for (int off = 32; off; off >>= 1) s += __shfl_down(s, off);
    if (lane == 0) red[wid] = s;
    __syncthreads();
    float mu = (red[0]+red[1]+red[2]+red[3]) * (1.f/512.f);
    __syncthreads();

    float d0 = v0 - mu, d1 = v1 - mu;
    float q = d0*d0 + d1*d1;
    #pragma unroll
    for (int off = 32; off; off >>= 1) q += __shfl_down(q, off);
    if (lane == 0) red[wid] = q;
    __syncthreads();
    float var = (red[0]+red[1]+red[2]+red[3]) * (1.f/512.f);
    float rs = rsqrtf(var + 1e-5f);

    float y0 = d0*rs*g[tid] + bb[tid];
    float y1 = d1*rs*g[tid+256] + bb[tid+256];
    y0 = 0.5f*y0*(1.f + erff(y0*0.70710678118654752f));
    y1 = 0.5f*y1*(1.f + erff(y1*0.70710678118654752f));
    h[row*512 + tid] = y0;
    h[row*512 + 256 + tid] = y1;
}

// ---------------- Kernel 3: aggregation ----------------
// z[(b*256+n)*1536 + t*512 + h] = V[0,t]*x[b,n,h] + sum_m coef(adj[b,n,m],t)*x[b,m,h]
// block: one b, 32-row n tile, 128-col h tile; loop m in 32-chunks.
__global__ __launch_bounds__(256) void agg(const float* __restrict__ x,
    const int* __restrict__ adj, const float* __restrict__ V,
    float* __restrict__ z)
{
    int b = blockIdx.z, ny = blockIdx.y, hx = blockIdx.x;
    int n0 = ny*32, h0 = hx*128;
    int tid = threadIdx.x;
    int tx = tid & 31, ty = tid >> 5;   // tx: 32 h-groups of 4, ty: 8 n-groups of 4
    __shared__ float xs[32][132];
    __shared__ float cs[3][32][33];
    __shared__ float Vs[16][3];
    if (tid < 48) Vs[tid/3][tid%3] = V[tid];

    float acc[3][4][4] = {};   // [t][n_i][h_j]
    const float* xb = x + b*NSEQ*HID;
    const int* adjb = adj + (b*NSEQ + n0)*NSEQ;

    for (int mt = 0; mt < 8; ++mt) {
        int m0 = mt*32;
        __syncthreads();  // protect LDS from previous iter readers (also covers Vs init)
        #pragma unroll
        for (int i = 0; i < 4; ++i) {
            int e = tid + i*256;
            int r = e >> 5, c = e & 31;
            int a = adjb[r*NSEQ + m0 + c];
            float c0 = 0.f, c1 = 0.f, c2 = 0.f;
            if (a >= 1) { c0 = Vs[a][0]; c1 = Vs[a][1]; c2 = Vs[a][2]; }
            cs[0][r][c] = c0; cs[1][r][c] = c1; cs[2][r][c] = c2;
        }
        #pragma unroll
        for (int i = 0; i < 4; ++i) {
            int e = tid + i*256;
            int r = e >> 5, c4 = e & 31;
            *(float4*)&xs[r][c4*4] = *(const float4*)&xb[(m0+r)*HID + h0 + c4*4];
        }
        __syncthreads();
        for (int j = 0; j < 32; ++j) {
            float xv[4];
            *(float4*)xv = *(float4*)&xs[j][tx*4];
            #pragma unroll
            for (int i = 0; i < 4; ++i) {
                int nr = ty*4 + i;
                float c0 = cs[0][nr][j], c1 = cs[1][nr][j], c2 = cs[2][nr][j];
                #pragma unroll
                for (int jj = 0; jj < 4; ++jj) {
                    acc[0][i][jj] += c0*xv[jj];
                    acc[1][i][jj] += c1*xv[jj];
                    acc[2][i][jj] += c2*xv[jj];
                }
            }
        }
    }
    #pragma unroll
    for (int i = 0; i < 4; ++i) {
        int n = n0 + ty*4 + i;
        float xv[4];
        *(float4*)xv = *(const float4*)&xb[n*HID + h0 + tx*4];
        #pragma unroll
        for (int t = 0; t < 3; ++t) {
            float vt = Vs[0][t];
            float o[4];
            #pragma unroll
            for (int jj = 0; jj < 4; ++jj) o[jj] = acc[t][i][jj] + vt*xv[jj];
            *(float4*)&z[((b*NSEQ + n)*3 + t)*HID + h0 + tx*4] = *(float4*)o;
        }
    }
}

// ---------------- Kernel 4: out GEMM: out = Z[8192,1536] @ W2[1536,512] ----------------
// W2[k][o] = W[h*1536 + t*512 + o] with k = t*512 + h
__global__ __launch_bounds__(256) void out_gemm(const float* __restrict__ z,
    const float* __restrict__ W, float* __restrict__ out)
{
    __shared__ float As[16][68];  // As[kk][row]
    __shared__ float Bs[16][68];
    int bx = blockIdx.x, by = blockIdx.y;
    int tid = threadIdx.x;
    int tx = tid & 15, ty = tid >> 4;
    int row0 = by*64, col0 = bx*64;
    float acc[4][4] = {};
    for (int kt = 0; kt < 96; ++kt) {
        int k0 = kt*16;
        {   // A tile via float4: 64 rows x 4 float4 = 256 loads, one per thread
            int r = tid >> 2, f4 = tid & 3;
            float a[4];
            *(float4*)a = *(const float4*)&z[(row0+r)*1536 + k0 + f4*4];
            #pragma unroll
            for (int q = 0; q < 4; ++q) As[f4*4+q][r] = a[q];
        }
        #pragma unroll
        for (int i = 0; i < 4; ++i) {
            int e = tid + i*256;
            int kk = e >> 6, c = e & 63;
            int k = k0 + kk;
            Bs[kk][c] = W[(k & 511)*1536 + (k >> 9)*512 + col0 + c];
        }
        __syncthreads();
        #pragma unroll
        for (int kk = 0; kk < 16; ++kk) {
            float a[4], b[4];
            *(float4*)a = *(float4*)&As[kk][ty*4];
            *(float4*)b = *(float4*)&Bs[kk][tx*4];
            #pragma unroll
            for (int i = 0; i < 4; ++i)
                #pragma unroll
                for (int j = 0; j < 4; ++j)
                    acc[i][j] += a[i]*b[j];
        }
        __syncthreads();
    }
    #pragma unroll
    for (int i = 0; i < 4; ++i) {
        int row = row0 + ty*4 + i;
        *(float4*)&out[row*512 + col0 + tx*4] =
            make_float4(acc[i][0], acc[i][1], acc[i][2], acc[i][3]);
    }
}

extern "C" void kernel_launch(void* const* d_in, const int* in_sizes, int n_in,
                              void* d_out, int out_size, void* d_ws, size_t ws_size,
                              hipStream_t stream)
{
    const float* cols   = (const float*)d_in[0];
    const float* logits = (const float*)d_in[1];
    const int*   adj    = (const int*)  d_in[2];
    const float* Wp     = (const float*)d_in[3];
    const float* bp     = (const float*)d_in[4];
    const float* lg     = (const float*)d_in[5];
    const float* lb     = (const float*)d_in[6];
    const float* W      = (const float*)d_in[7];
    const float* V      = (const float*)d_in[8];
    float* out  = (float*)d_out;
    float* xbuf = (float*)d_ws;                     // 8192*512 f32 = 16.8 MB
    float* zbuf = xbuf + (size_t)ROWS*HID;          // 8192*1536 f32 = 50.3 MB

    proj_gemm<<<dim3(8,128), 256, 0, stream>>>(cols, logits, Wp, bp, xbuf);
    ln_gelu <<<ROWS, 256, 0, stream>>>(xbuf, lg, lb);
    agg     <<<dim3(4,8,32), 256, 0, stream>>>(xbuf, adj, V, zbuf);
    out_gemm<<<dim3(8,128), 256, 0, stream>>>(zbuf, W, out);
}

// Round 2
// 220.599 us; speedup vs baseline: 1.6999x; 1.6999x over previous
//
#include <hip/hip_runtime.h>
#include <math.h>

#define HID 512
#define NSEQ 256
#define BSZ 32
#define ROWS (BSZ*NSEQ)   // 8192
#define KTOT 1536

typedef _Float16 half8_t __attribute__((ext_vector_type(8)));
typedef _Float16 half4_t __attribute__((ext_vector_type(4)));
typedef float f32x4 __attribute__((ext_vector_type(4)));

__device__ __forceinline__ void gload16(const _Float16* g, _Float16* l) {
    __builtin_amdgcn_global_load_lds(
        (const __attribute__((address_space(1))) unsigned int*)g,
        (__attribute__((address_space(3))) unsigned int*)l, 16, 0, 0);
}

// ---------------- Kernel 0: Whc[o][k] = f16(W[h][t][o]), k = t*512+h ----------------
__global__ __launch_bounds__(256) void convW(const float* __restrict__ W,
                                             _Float16* __restrict__ Whc)
{
    int k = blockIdx.x * 256 + threadIdx.x;   // grid.x = 6 -> k in [0,1536)
    int o = blockIdx.y;                        // 512
    int h = k & 511, t = k >> 9;
    Whc[(size_t)o * KTOT + k] = (_Float16)W[(size_t)h * KTOT + t * 512 + o];
}

// ---------------- Kernel 1: proj GEMM: h = concat(columns,logits) @ Wp + bp ----------
__global__ __launch_bounds__(256) void proj_gemm(const float* __restrict__ cols,
    const float* __restrict__ logits, const float* __restrict__ Wp,
    const float* __restrict__ bp, float* __restrict__ hout)
{
    __shared__ float As[16][68];  // transposed: As[kk][row]
    __shared__ float Bs[16][68];
    int bx = blockIdx.x;
    int by = blockIdx.y;
    int tid = threadIdx.x;
    int tx = tid & 15, ty = tid >> 4;
    int row0 = by*64, col0 = bx*64;
    float acc[4][4] = {};
    for (int kt = 0; kt < 33; ++kt) {
        int k0 = kt*16;
        #pragma unroll
        for (int i = 0; i < 4; ++i) {
            int e = tid + i*256;
            int r = e >> 4, kk = e & 15;
            int k = k0 + kk;
            int row = row0 + r;
            float v = 0.f;
            if (k < 512) v = cols[row*512 + k];
            else if (k < 514) v = logits[row*2 + (k-512)];
            As[kk][r] = v;
        }
        #pragma unroll
        for (int i = 0; i < 4; ++i) {
            int e = tid + i*256;
            int kk = e >> 6, c = e & 63;
            int k = k0 + kk;
            float v = 0.f;
            if (k < 514) v = Wp[k*512 + col0 + c];
            Bs[kk][c] = v;
        }
        __syncthreads();
        #pragma unroll
        for (int kk = 0; kk < 16; ++kk) {
            float a[4], b[4];
            *(float4*)a = *(float4*)&As[kk][ty*4];
            *(float4*)b = *(float4*)&Bs[kk][tx*4];
            #pragma unroll
            for (int i = 0; i < 4; ++i)
                #pragma unroll
                for (int j = 0; j < 4; ++j)
                    acc[i][j] += a[i]*b[j];
        }
        __syncthreads();
    }
    #pragma unroll
    for (int i = 0; i < 4; ++i) {
        int row = row0 + ty*4 + i;
        float o[4];
        #pragma unroll
        for (int j = 0; j < 4; ++j)
            o[j] = acc[i][j] + bp[col0 + tx*4 + j];
        *(float4*)&hout[row*512 + col0 + tx*4] = *(float4*)o;
    }
}

// ---------------- Kernel 2: LayerNorm + exact GELU, in-place ----------------
__global__ __launch_bounds__(256) void ln_gelu(float* __restrict__ h,
    const float* __restrict__ g, const float* __restrict__ bb)
{
    int row = blockIdx.x;
    int tid = threadIdx.x;
    float v0 = h[row*512 + tid];
    float v1 = h[row*512 + 256 + tid];
    __shared__ float red[4];
    int wid = tid >> 6, lane = tid & 63;

    float s = v0 + v1;
    #pragma unroll
    for (int off = 32; off; off >>= 1) s += __shfl_down(s, off);
    if (lane == 0) red[wid] = s;
    __syncthreads();
    float mu = (red[0]+red[1]+red[2]+red[3]) * (1.f/512.f);
    __syncthreads();

    float d0 = v0 - mu, d1 = v1 - mu;
    float q = d0*d0 + d1*d1;
    #pragma unroll
    for (int off = 32; off; off >>= 1) q += __shfl_down(q, off);
    if (lane == 0) red[wid] = q;
    __syncthreads();
    float var = (red[0]+red[1]+red[2]+red[3]) * (1.f/512.f);
    float rs = rsqrtf(var + 1e-5f);

    float y0 = d0*rs*g[tid] + bb[tid];
    float y1 = d1*rs*g[tid+256] + bb[tid+256];
    y0 = 0.5f*y0*(1.f + erff(y0*0.70710678118654752f));
    y1 = 0.5f*y1*(1.f + erff(y1*0.70710678118654752f));
    h[row*512 + tid] = y0;
    h[row*512 + 256 + tid] = y1;
}

// ---------------- Kernel 3: aggregation -> z (f16) ----------------
// z[(b*256+n)*1536 + t*512 + h] = V[0,t]*x[b,n,h] + sum_m coef(adj[b,n,m],t)*x[b,m,h]
__global__ __launch_bounds__(256) void agg(const float* __restrict__ x,
    const int* __restrict__ adj, const float* __restrict__ V,
    _Float16* __restrict__ z)
{
    int b = blockIdx.z, ny = blockIdx.y, hx = blockIdx.x;
    int n0 = ny*32, h0 = hx*128;
    int tid = threadIdx.x;
    int tx = tid & 31, ty = tid >> 5;
    __shared__ float xs[32][132];
    __shared__ float cs[3][32][33];
    __shared__ float Vs[16][3];
    if (tid < 48) Vs[tid/3][tid%3] = V[tid];

    float acc[3][4][4] = {};   // [t][n_i][h_j]
    const float* xb = x + b*NSEQ*HID;
    const int* adjb = adj + (b*NSEQ + n0)*NSEQ;

    for (int mt = 0; mt < 8; ++mt) {
        int m0 = mt*32;
        __syncthreads();
        #pragma unroll
        for (int i = 0; i < 4; ++i) {
            int e = tid + i*256;
            int r = e >> 5, c = e & 31;
            int a = adjb[r*NSEQ + m0 + c];
            float c0 = 0.f, c1 = 0.f, c2 = 0.f;
            if (a >= 1) { c0 = Vs[a][0]; c1 = Vs[a][1]; c2 = Vs[a][2]; }
            cs[0][r][c] = c0; cs[1][r][c] = c1; cs[2][r][c] = c2;
        }
        #pragma unroll
        for (int i = 0; i < 4; ++i) {
            int e = tid + i*256;
            int r = e >> 5, c4 = e & 31;
            *(float4*)&xs[r][c4*4] = *(const float4*)&xb[(m0+r)*HID + h0 + c4*4];
        }
        __syncthreads();
        for (int j = 0; j < 32; ++j) {
            float xv[4];
            *(float4*)xv = *(float4*)&xs[j][tx*4];
            #pragma unroll
            for (int i = 0; i < 4; ++i) {
                int nr = ty*4 + i;
                float c0 = cs[0][nr][j], c1 = cs[1][nr][j], c2 = cs[2][nr][j];
                #pragma unroll
                for (int jj = 0; jj < 4; ++jj) {
                    acc[0][i][jj] += c0*xv[jj];
                    acc[1][i][jj] += c1*xv[jj];
                    acc[2][i][jj] += c2*xv[jj];
                }
            }
        }
    }
    #pragma unroll
    for (int i = 0; i < 4; ++i) {
        int n = n0 + ty*4 + i;
        float xv[4];
        *(float4*)xv = *(const float4*)&xb[n*HID + h0 + tx*4];
        #pragma unroll
        for (int t = 0; t < 3; ++t) {
            float vt = Vs[0][t];
            half4_t o;
            #pragma unroll
            for (int jj = 0; jj < 4; ++jj) o[jj] = (_Float16)(acc[t][i][jj] + vt*xv[jj]);
            *(half4_t*)&z[((size_t)(b*NSEQ + n)*3 + t)*HID + h0 + tx*4] = o;
        }
    }
}

// ---------------- Kernel 4: out = Z[8192,1536](f16) @ Whc^T, MFMA f16 ----------------
// Whc is [512 o][1536 k]. Tiles: BM=128, BN=128, BK=64. 4 waves (2x2), 64x64 per wave.
__global__ __launch_bounds__(256) void out_gemm_mfma(
    const _Float16* __restrict__ z, const _Float16* __restrict__ Whc,
    float* __restrict__ out)
{
    __shared__ _Float16 As[2][128*64];
    __shared__ _Float16 Bs[2][128*64];
    const int tid = threadIdx.x;
    const int w = tid >> 6, lane = tid & 63;
    const int row0 = blockIdx.y * 128, col0 = blockIdx.x * 128;
    const int wr = (w >> 1) * 64, wc = (w & 1) * 64;
    const _Float16* Ag = z   + (size_t)row0 * KTOT;
    const _Float16* Bg = Whc + (size_t)col0 * KTOT;

    f32x4 acc[4][4] = {};

    // stage one 128x64 f16 tile; content swizzled so ds_read_b128 is bank-uniform:
    // physical granule (row, c) holds logical (row, c ^ (row&7)).
    auto stage = [&](const _Float16* gbase, _Float16* lds) {
        #pragma unroll
        for (int l = 0; l < 4; ++l) {
            int gw = l * 256 + w * 64;      // wave-uniform granule base
            int g  = gw + lane;
            int row = g >> 3;
            int c   = (g & 7) ^ (row & 7);  // pre-swizzled global source
            gload16(gbase + (size_t)row * KTOT + c * 8, lds + (size_t)gw * 8);
        }
    };

    stage(Ag, As[0]);
    stage(Bg, Bs[0]);
    asm volatile("s_waitcnt vmcnt(0)" ::: "memory");
    __syncthreads();

    int buf = 0;
    for (int kt = 0; kt < 24; ++kt) {
        if (kt < 23) {
            stage(Ag + (kt + 1) * 64, As[buf ^ 1]);
            stage(Bg + (kt + 1) * 64, Bs[buf ^ 1]);
        }
        const _Float16* Ab = As[buf];
        const _Float16* Bb = Bs[buf];
        const int r16 = lane & 15;
        #pragma unroll
        for (int kh = 0; kh < 2; ++kh) {
            const int ks = (lane >> 4) + kh * 4;
            half8_t a[4], b[4];
            #pragma unroll
            for (int mi = 0; mi < 4; ++mi) {
                int row = wr + mi * 16 + r16;
                a[mi] = *(const half8_t*)(Ab + row * 64 + ((ks ^ (row & 7)) * 8));
            }
            #pragma unroll
            for (int ni = 0; ni < 4; ++ni) {
                int col = wc + ni * 16 + r16;
                b[ni] = *(const half8_t*)(Bb + col * 64 + ((ks ^ (col & 7)) * 8));
            }
            #pragma unroll
            for (int mi = 0; mi < 4; ++mi)
                #pragma unroll
                for (int ni = 0; ni < 4; ++ni)
                    acc[mi][ni] = __builtin_amdgcn_mfma_f32_16x16x32_f16(
                        a[mi], b[ni], acc[mi][ni], 0, 0, 0);
        }
        if (kt < 23) asm volatile("s_waitcnt vmcnt(0)" ::: "memory");
        __syncthreads();
        buf ^= 1;
    }

    // C/D layout: col = lane&15, row = (lane>>4)*4 + q
    #pragma unroll
    for (int mi = 0; mi < 4; ++mi) {
        int r = row0 + wr + mi * 16 + (lane >> 4) * 4;
        #pragma unroll
        for (int ni = 0; ni < 4; ++ni) {
            int cidx = col0 + wc + ni * 16 + (lane & 15);
            #pragma unroll
            for (int q = 0; q < 4; ++q)
                out[(size_t)(r + q) * 512 + cidx] = acc[mi][ni][q];
        }
    }
}

extern "C" void kernel_launch(void* const* d_in, const int* in_sizes, int n_in,
                              void* d_out, int out_size, void* d_ws, size_t ws_size,
                              hipStream_t stream)
{
    const float* cols   = (const float*)d_in[0];
    const float* logits = (const float*)d_in[1];
    const int*   adj    = (const int*)  d_in[2];
    const float* Wp     = (const float*)d_in[3];
    const float* bp     = (const float*)d_in[4];
    const float* lg     = (const float*)d_in[5];
    const float* lb     = (const float*)d_in[6];
    const float* W      = (const float*)d_in[7];
    const float* V      = (const float*)d_in[8];
    float* out  = (float*)d_out;

    float*    xbuf = (float*)d_ws;                               // 16.8 MB f32
    _Float16* zbuf = (_Float16*)((char*)d_ws + (size_t)ROWS*HID*4);      // 25.2 MB f16
    _Float16* Whc  = zbuf + (size_t)ROWS*KTOT;                   // 1.6 MB f16

    convW    <<<dim3(6,512), 256, 0, stream>>>(W, Whc);
    proj_gemm<<<dim3(8,128), 256, 0, stream>>>(cols, logits, Wp, bp, xbuf);
    ln_gelu  <<<ROWS, 256, 0, stream>>>(xbuf, lg, lb);
    agg      <<<dim3(4,8,32), 256, 0, stream>>>(xbuf, adj, V, zbuf);
    out_gemm_mfma<<<dim3(4,64), 256, 0, stream>>>(zbuf, Whc, out);
}

// Round 3
// 118.323 us; speedup vs baseline: 3.1692x; 1.8644x over previous
//
#include <hip/hip_runtime.h>
#include <math.h>

#define HID 512
#define NSEQ 256
#define BSZ 32
#define ROWS (BSZ*NSEQ)   // 8192
#define KTOT 1536
#define KP 576            // padded proj K (514 -> 576 = 9*64)

typedef _Float16 half8_t __attribute__((ext_vector_type(8)));
typedef _Float16 half4_t __attribute__((ext_vector_type(4)));
typedef float f32x4 __attribute__((ext_vector_type(4)));

__device__ __forceinline__ void gload16(const _Float16* g, _Float16* l) {
    __builtin_amdgcn_global_load_lds(
        (const __attribute__((address_space(1))) unsigned int*)g,
        (__attribute__((address_space(3))) unsigned int*)l, 16, 0, 0);
}

// ---------------- Whc[o][k] = f16(W[h][t][o]), k = t*512+h ----------------
__global__ __launch_bounds__(256) void convW(const float* __restrict__ W,
                                             _Float16* __restrict__ Whc)
{
    int k = blockIdx.x * 256 + threadIdx.x;   // grid.x = 6
    int o = blockIdx.y;                        // 512
    int h = k & 511, t = k >> 9;
    Whc[(size_t)o * KTOT + k] = (_Float16)W[(size_t)h * KTOT + t * 512 + o];
}

// ---------------- Acat[row][k] = f16 concat(columns,logits), zero pad to KP --------
__global__ __launch_bounds__(256) void cat_inp(const float* __restrict__ cols,
    const float* __restrict__ logits, _Float16* __restrict__ Acat)
{
    int row = blockIdx.x;
    for (int k = threadIdx.x; k < KP; k += 256) {
        float v = 0.f;
        if (k < 512) v = cols[(size_t)row * 512 + k];
        else if (k < 514) v = logits[(size_t)row * 2 + (k - 512)];
        Acat[(size_t)row * KP + k] = (_Float16)v;
    }
}

// ---------------- WpT[o][k] = f16(Wp[k][o]), k padded 514->KP with zeros ----------
__global__ __launch_bounds__(256) void transW(const float* __restrict__ Wp,
                                              _Float16* __restrict__ WpT)
{
    __shared__ _Float16 ts[64][68];   // [k in tile][o in tile]
    int k0 = blockIdx.x * 64, o0 = blockIdx.y * 64;  // grid (9, 8)
    int tid = threadIdx.x;
    int r = tid >> 2, q = tid & 3;
    int k = k0 + r;
    #pragma unroll
    for (int i = 0; i < 4; ++i) {
        float4 v = make_float4(0.f, 0.f, 0.f, 0.f);
        if (k < 514) v = *(const float4*)&Wp[(size_t)k * HID + o0 + q * 16 + i * 4];
        ts[r][q*16 + i*4 + 0] = (_Float16)v.x;
        ts[r][q*16 + i*4 + 1] = (_Float16)v.y;
        ts[r][q*16 + i*4 + 2] = (_Float16)v.z;
        ts[r][q*16 + i*4 + 3] = (_Float16)v.w;
    }
    __syncthreads();
    _Float16* op = WpT + (size_t)(o0 + r) * KP + k0 + q * 16;
    #pragma unroll
    for (int i = 0; i < 4; ++i) {
        half4_t o;
        #pragma unroll
        for (int j = 0; j < 4; ++j) o[j] = ts[q*16 + i*4 + j][r];
        *(half4_t*)(op + i * 4) = o;
    }
}

// ---------------- generic 128x128 f16 MFMA GEMM (A[M][KS], B[N][KS], out f32 [M][512]) --
template<int KS, int NKT, bool BIAS>
__global__ __launch_bounds__(256) void gemm_f16(
    const _Float16* __restrict__ A, const _Float16* __restrict__ Bm,
    const float* __restrict__ bias, float* __restrict__ out)
{
    __shared__ _Float16 As[2][128*64];
    __shared__ _Float16 Bs[2][128*64];
    const int tid = threadIdx.x;
    const int w = tid >> 6, lane = tid & 63;
    const int row0 = blockIdx.y * 128, col0 = blockIdx.x * 128;
    const int wr = (w >> 1) * 64, wc = (w & 1) * 64;
    const _Float16* Ag = A  + (size_t)row0 * KS;
    const _Float16* Bg = Bm + (size_t)col0 * KS;

    f32x4 acc[4][4] = {};

    auto stage = [&](const _Float16* gbase, _Float16* lds) {
        #pragma unroll
        for (int l = 0; l < 4; ++l) {
            int gw = l * 256 + w * 64;
            int g  = gw + lane;
            int row = g >> 3;
            int c   = (g & 7) ^ (row & 7);
            gload16(gbase + (size_t)row * KS + c * 8, lds + (size_t)gw * 8);
        }
    };

    stage(Ag, As[0]);
    stage(Bg, Bs[0]);
    asm volatile("s_waitcnt vmcnt(0)" ::: "memory");
    __syncthreads();

    int buf = 0;
    for (int kt = 0; kt < NKT; ++kt) {
        if (kt < NKT-1) {
            stage(Ag + (kt + 1) * 64, As[buf ^ 1]);
            stage(Bg + (kt + 1) * 64, Bs[buf ^ 1]);
        }
        const _Float16* Ab = As[buf];
        const _Float16* Bb = Bs[buf];
        const int r16 = lane & 15;
        #pragma unroll
        for (int kh = 0; kh < 2; ++kh) {
            const int ks = (lane >> 4) + kh * 4;
            half8_t a[4], b[4];
            #pragma unroll
            for (int mi = 0; mi < 4; ++mi) {
                int row = wr + mi * 16 + r16;
                a[mi] = *(const half8_t*)(Ab + row * 64 + ((ks ^ (row & 7)) * 8));
            }
            #pragma unroll
            for (int ni = 0; ni < 4; ++ni) {
                int col = wc + ni * 16 + r16;
                b[ni] = *(const half8_t*)(Bb + col * 64 + ((ks ^ (col & 7)) * 8));
            }
            #pragma unroll
            for (int mi = 0; mi < 4; ++mi)
                #pragma unroll
                for (int ni = 0; ni < 4; ++ni)
                    acc[mi][ni] = __builtin_amdgcn_mfma_f32_16x16x32_f16(
                        a[mi], b[ni], acc[mi][ni], 0, 0, 0);
        }
        if (kt < NKT-1) asm volatile("s_waitcnt vmcnt(0)" ::: "memory");
        __syncthreads();
        buf ^= 1;
    }

    #pragma unroll
    for (int mi = 0; mi < 4; ++mi) {
        int r = row0 + wr + mi * 16 + (lane >> 4) * 4;
        #pragma unroll
        for (int ni = 0; ni < 4; ++ni) {
            int cidx = col0 + wc + ni * 16 + (lane & 15);
            float bv = BIAS ? bias[cidx] : 0.f;
            #pragma unroll
            for (int q = 0; q < 4; ++q)
                out[(size_t)(r + q) * HID + cidx] = acc[mi][ni][q] + bv;
        }
    }
}

// ---------------- LayerNorm + exact GELU, in-place on f32 ----------------
__global__ __launch_bounds__(256) void ln_gelu(float* __restrict__ h,
    const float* __restrict__ g, const float* __restrict__ bb)
{
    int row = blockIdx.x;
    int tid = threadIdx.x;
    float v0 = h[row*512 + tid];
    float v1 = h[row*512 + 256 + tid];
    __shared__ float red[4];
    int wid = tid >> 6, lane = tid & 63;

    float s = v0 + v1;
    #pragma unroll
    for (int off = 32; off; off >>= 1) s += __shfl_down(s, off);
    if (lane == 0) red[wid] = s;
    __syncthreads();
    float mu = (red[0]+red[1]+red[2]+red[3]) * (1.f/512.f);
    __syncthreads();

    float d0 = v0 - mu, d1 = v1 - mu;
    float q = d0*d0 + d1*d1;
    #pragma unroll
    for (int off = 32; off; off >>= 1) q += __shfl_down(q, off);
    if (lane == 0) red[wid] = q;
    __syncthreads();
    float var = (red[0]+red[1]+red[2]+red[3]) * (1.f/512.f);
    float rs = rsqrtf(var + 1e-5f);

    float y0 = d0*rs*g[tid] + bb[tid];
    float y1 = d1*rs*g[tid+256] + bb[tid+256];
    y0 = 0.5f*y0*(1.f + erff(y0*0.70710678118654752f));
    y1 = 0.5f*y1*(1.f + erff(y1*0.70710678118654752f));
    h[row*512 + tid] = y0;
    h[row*512 + 256 + tid] = y1;
}

// ---------------- XT[b][h][n] = f16(x[b][n][h]) ----------------
__global__ __launch_bounds__(256) void transpose_x(const float* __restrict__ x,
    _Float16* __restrict__ XT)
{
    __shared__ _Float16 ts[64][68];   // [n in tile][h in tile]
    int b = blockIdx.z;
    int n0 = blockIdx.y * 64, h0 = blockIdx.x * 64;  // grid (8, 4, 32)
    int tid = threadIdx.x;
    int r = tid >> 2, q = tid & 3;
    const float* xp = x + ((size_t)(b*NSEQ + n0 + r)) * HID + h0 + q * 16;
    #pragma unroll
    for (int i = 0; i < 4; ++i) {
        float4 v = *(const float4*)(xp + i * 4);
        ts[r][q*16 + i*4 + 0] = (_Float16)v.x;
        ts[r][q*16 + i*4 + 1] = (_Float16)v.y;
        ts[r][q*16 + i*4 + 2] = (_Float16)v.z;
        ts[r][q*16 + i*4 + 3] = (_Float16)v.w;
    }
    __syncthreads();
    _Float16* op = XT + (size_t)b*(HID*NSEQ) + (size_t)(h0 + r)*NSEQ + n0 + q*16;
    #pragma unroll
    for (int i = 0; i < 4; ++i) {
        half4_t o;
        #pragma unroll
        for (int j = 0; j < 4; ++j) o[j] = ts[q*16 + i*4 + j][r];
        *(half4_t*)(op + i * 4) = o;
    }
}

// ---------------- C16[b][t][n][m] = f16( (adj>=1 ? V[adj][t] : 0) + (n==m)*V[0][t] ) ----
__global__ __launch_bounds__(256) void buildC(const int* __restrict__ adj,
    const float* __restrict__ V, _Float16* __restrict__ C16)
{
    __shared__ float lut[16][3];
    __shared__ float V0[3];
    int tid = threadIdx.x;
    if (tid < 48) { int r = tid / 3, c = tid - r * 3; lut[r][c] = (r >= 1) ? V[tid] : 0.f; }
    if (tid < 3) V0[tid] = V[tid];
    __syncthreads();
    int b = blockIdx.y;
    int n = blockIdx.x * 64 + (tid >> 2), mq = tid & 3;   // grid (4, 32)
    const int* ap = adj + ((size_t)(b*NSEQ + n)) * NSEQ + mq * 64;
    size_t obase = ((size_t)(b*3) << 16) + (size_t)n * 256 + mq * 64;
    #pragma unroll
    for (int i = 0; i < 16; ++i) {
        int4 a4 = *(const int4*)(ap + i * 4);
        int av[4] = { a4.x, a4.y, a4.z, a4.w };
        #pragma unroll
        for (int t = 0; t < 3; ++t) {
            half4_t o;
            #pragma unroll
            for (int j = 0; j < 4; ++j) {
                int m = mq * 64 + i * 4 + j;
                float v = lut[av[j]][t] + ((m == n) ? V0[t] : 0.f);
                o[j] = (_Float16)v;
            }
            *(half4_t*)(C16 + obase + ((size_t)t << 16) + i * 4) = o;
        }
    }
}

// ---------------- agg: Z_t[b] = C16[b][t] @ X[b]  (M=256 n, N=512 h, K=256 m) --------
// per block: 128n x 128h for one (b,t). Output written f16 via LDS repack.
__global__ __launch_bounds__(256) void agg_mfma(
    const _Float16* __restrict__ C16, const _Float16* __restrict__ XT,
    _Float16* __restrict__ z)
{
    __shared__ _Float16 smem[32768];   // 64KB: As0|As1|Bs0|Bs1 (8192 f16 each)
    const int tid = threadIdx.x;
    const int w = tid >> 6, lane = tid & 63;
    const int bz = blockIdx.z;                 // b*3 + trel
    const int b = bz / 3, trel = bz - b * 3;
    const int n0 = blockIdx.y * 128, h0 = blockIdx.x * 128;  // grid (4, 2, 96)
    const int wr = (w >> 1) * 64, wc = (w & 1) * 64;
    const _Float16* Ag = C16 + ((size_t)bz << 16) + (size_t)n0 * 256;
    const _Float16* Bg = XT + (size_t)b * (HID*NSEQ) + (size_t)h0 * 256;

    f32x4 acc[4][4] = {};

    auto stage = [&](const _Float16* gbase, _Float16* lds) {
        #pragma unroll
        for (int l = 0; l < 4; ++l) {
            int gw = l * 256 + w * 64;
            int g  = gw + lane;
            int row = g >> 3;
            int c   = (g & 7) ^ (row & 7);
            gload16(gbase + (size_t)row * 256 + c * 8, lds + (size_t)gw * 8);
        }
    };

    stage(Ag, smem);            // As0
    stage(Bg, smem + 16384);    // Bs0
    asm volatile("s_waitcnt vmcnt(0)" ::: "memory");
    __syncthreads();

    int buf = 0;
    for (int kt = 0; kt < 4; ++kt) {
        if (kt < 3) {
            stage(Ag + (kt + 1) * 64, smem + (buf ^ 1) * 8192);
            stage(Bg + (kt + 1) * 64, smem + 16384 + (buf ^ 1) * 8192);
        }
        const _Float16* Ab = smem + buf * 8192;
        const _Float16* Bb = smem + 16384 + buf * 8192;
        const int r16 = lane & 15;
        #pragma unroll
        for (int kh = 0; kh < 2; ++kh) {
            const int ks = (lane >> 4) + kh * 4;
            half8_t a[4], bf[4];
            #pragma unroll
            for (int mi = 0; mi < 4; ++mi) {
                int row = wr + mi * 16 + r16;
                a[mi] = *(const half8_t*)(Ab + row * 64 + ((ks ^ (row & 7)) * 8));
            }
            #pragma unroll
            for (int ni = 0; ni < 4; ++ni) {
                int col = wc + ni * 16 + r16;
                bf[ni] = *(const half8_t*)(Bb + col * 64 + ((ks ^ (col & 7)) * 8));
            }
            #pragma unroll
            for (int mi = 0; mi < 4; ++mi)
                #pragma unroll
                for (int ni = 0; ni < 4; ++ni)
                    acc[mi][ni] = __builtin_amdgcn_mfma_f32_16x16x32_f16(
                        a[mi], bf[ni], acc[mi][ni], 0, 0, 0);
        }
        if (kt < 3) asm volatile("s_waitcnt vmcnt(0)" ::: "memory");
        __syncthreads();
        buf ^= 1;
    }

    // repack acc -> smem[0..16384) as [128 n][128 h] f16 (safe: barrier passed)
    #pragma unroll
    for (int mi = 0; mi < 4; ++mi) {
        int rbase = wr + mi * 16 + (lane >> 4) * 4;
        #pragma unroll
        for (int ni = 0; ni < 4; ++ni) {
            int col = wc + ni * 16 + (lane & 15);
            #pragma unroll
            for (int q = 0; q < 4; ++q)
                smem[(rbase + q) * 128 + col] = (_Float16)acc[mi][ni][q];
        }
    }
    __syncthreads();

    // coalesced copy: 2048 granules of 16B
    _Float16* zb = z + ((size_t)(b*NSEQ + n0)) * KTOT + trel * 512 + h0;
    #pragma unroll
    for (int i = 0; i < 8; ++i) {
        int g = i * 256 + tid;
        int row = g >> 4, hoff = (g & 15) * 8;
        *(half8_t*)(zb + (size_t)row * KTOT + hoff) = *(const half8_t*)(smem + g * 8);
    }
}

extern "C" void kernel_launch(void* const* d_in, const int* in_sizes, int n_in,
                              void* d_out, int out_size, void* d_ws, size_t ws_size,
                              hipStream_t stream)
{
    const float* cols   = (const float*)d_in[0];
    const float* logits = (const float*)d_in[1];
    const int*   adj    = (const int*)  d_in[2];
    const float* Wp     = (const float*)d_in[3];
    const float* bp     = (const float*)d_in[4];
    const float* lg     = (const float*)d_in[5];
    const float* lb     = (const float*)d_in[6];
    const float* W      = (const float*)d_in[7];
    const float* V      = (const float*)d_in[8];
    float* out  = (float*)d_out;

    float* xbuf = (float*)d_ws;                                       // 16.8 MB
    char* p = (char*)d_ws + (size_t)ROWS*HID*4;
    _Float16* zbuf = (_Float16*)p;  p += (size_t)ROWS*KTOT*2;         // 25.2 MB
    _Float16* Whc  = (_Float16*)p;  p += (size_t)HID*KTOT*2;          // 1.6 MB
    _Float16* XT   = (_Float16*)p;  p += (size_t)BSZ*HID*NSEQ*2;      // 8.4 MB
    _Float16* C16  = (_Float16*)p;  p += (size_t)BSZ*3*NSEQ*NSEQ*2;   // 12.6 MB
    _Float16* Acat = (_Float16*)p;  p += (size_t)ROWS*KP*2;           // 9.4 MB
    _Float16* WpT  = (_Float16*)p;                                    // 0.6 MB

    convW      <<<dim3(6,512), 256, 0, stream>>>(W, Whc);
    cat_inp    <<<dim3(ROWS), 256, 0, stream>>>(cols, logits, Acat);
    transW     <<<dim3(9,8), 256, 0, stream>>>(Wp, WpT);
    gemm_f16<KP,9,true><<<dim3(4,64), 256, 0, stream>>>(Acat, WpT, bp, xbuf);
    ln_gelu    <<<ROWS, 256, 0, stream>>>(xbuf, lg, lb);
    transpose_x<<<dim3(8,4,32), 256, 0, stream>>>(xbuf, XT);
    buildC     <<<dim3(4,32), 256, 0, stream>>>(adj, V, C16);
    agg_mfma   <<<dim3(4,2,96), 256, 0, stream>>>(C16, XT, zbuf);
    gemm_f16<KTOT,24,false><<<dim3(4,64), 256, 0, stream>>>(zbuf, Whc, nullptr, out);
}

// Round 4
// 111.695 us; speedup vs baseline: 3.3573x; 1.0593x over previous
//
#include <hip/hip_runtime.h>
#include <math.h>

#define HID 512
#define NSEQ 256
#define BSZ 32
#define ROWS (BSZ*NSEQ)   // 8192
#define KTOT 1536
#define KP 576            // padded proj K (514 -> 576 = 9*64)

typedef _Float16 half8_t __attribute__((ext_vector_type(8)));
typedef _Float16 half4_t __attribute__((ext_vector_type(4)));
typedef float f32x4 __attribute__((ext_vector_type(4)));

__device__ __forceinline__ void gload16(const _Float16* g, _Float16* l) {
    __builtin_amdgcn_global_load_lds(
        (const __attribute__((address_space(1))) unsigned int*)g,
        (__attribute__((address_space(3))) unsigned int*)l, 16, 0, 0);
}

// ---------------- Whc[o][k] = f16(W[h][t][o]), k = t*512+h ----------------
__global__ __launch_bounds__(256) void convW(const float* __restrict__ W,
                                             _Float16* __restrict__ Whc)
{
    int k = blockIdx.x * 256 + threadIdx.x;   // grid.x = 6
    int o = blockIdx.y;                        // 512
    int h = k & 511, t = k >> 9;
    Whc[(size_t)o * KTOT + k] = (_Float16)W[(size_t)h * KTOT + t * 512 + o];
}

// ---------------- Acat[row][k] = f16 concat(columns,logits), zero pad to KP --------
__global__ __launch_bounds__(256) void cat_inp(const float* __restrict__ cols,
    const float* __restrict__ logits, _Float16* __restrict__ Acat)
{
    int row = blockIdx.x;
    for (int k = threadIdx.x; k < KP; k += 256) {
        float v = 0.f;
        if (k < 512) v = cols[(size_t)row * 512 + k];
        else if (k < 514) v = logits[(size_t)row * 2 + (k - 512)];
        Acat[(size_t)row * KP + k] = (_Float16)v;
    }
}

// ---------------- WpT[o][k] = f16(Wp[k][o]), k padded 514->KP with zeros ----------
__global__ __launch_bounds__(256) void transW(const float* __restrict__ Wp,
                                              _Float16* __restrict__ WpT)
{
    __shared__ _Float16 ts[64][68];   // [k in tile][o in tile]
    int k0 = blockIdx.x * 64, o0 = blockIdx.y * 64;  // grid (9, 8)
    int tid = threadIdx.x;
    int r = tid >> 2, q = tid & 3;
    int k = k0 + r;
    #pragma unroll
    for (int i = 0; i < 4; ++i) {
        float4 v = make_float4(0.f, 0.f, 0.f, 0.f);
        if (k < 514) v = *(const float4*)&Wp[(size_t)k * HID + o0 + q * 16 + i * 4];
        ts[r][q*16 + i*4 + 0] = (_Float16)v.x;
        ts[r][q*16 + i*4 + 1] = (_Float16)v.y;
        ts[r][q*16 + i*4 + 2] = (_Float16)v.z;
        ts[r][q*16 + i*4 + 3] = (_Float16)v.w;
    }
    __syncthreads();
    _Float16* op = WpT + (size_t)(o0 + r) * KP + k0 + q * 16;
    #pragma unroll
    for (int i = 0; i < 4; ++i) {
        half4_t o;
        #pragma unroll
        for (int j = 0; j < 4; ++j) o[j] = ts[q*16 + i*4 + j][r];
        *(half4_t*)(op + i * 4) = o;
    }
}

// ------------- 128x128 f16 MFMA GEMM, 3-deep counted-vmcnt pipeline --------------
// A[M][KS], B[N][KS], out f32 [M][512]. Grid (N/128, M/128). 8 gloads/wave/tile.
template<int KS, int NKT, bool BIAS>
__global__ __launch_bounds__(256) void gemm_f16p(
    const _Float16* __restrict__ A, const _Float16* __restrict__ Bm,
    const float* __restrict__ bias, float* __restrict__ out)
{
    __shared__ _Float16 As[3][128*64];   // 48KB
    __shared__ _Float16 Bs[3][128*64];   // 48KB
    const int tid = threadIdx.x;
    const int w = tid >> 6, lane = tid & 63;
    const int row0 = blockIdx.y * 128, col0 = blockIdx.x * 128;
    const int wr = (w >> 1) * 64, wc = (w & 1) * 64;
    const _Float16* Ag = A  + (size_t)row0 * KS;
    const _Float16* Bg = Bm + (size_t)col0 * KS;

    f32x4 acc[4][4] = {};

    // stage tile kt into buffer bi. LDS dest is linear; global source pre-swizzled:
    // physical granule (row, c) holds logical (row, c ^ (row&7)).
    auto stage = [&](int kt, int bi) {
        const _Float16* ga = Ag + kt * 64;
        const _Float16* gb = Bg + kt * 64;
        #pragma unroll
        for (int l = 0; l < 4; ++l) {
            int gw = l * 256 + w * 64;
            int g  = gw + lane;
            int row = g >> 3;
            int c   = (g & 7) ^ (row & 7);
            gload16(ga + (size_t)row * KS + c * 8, As[bi] + gw * 8);
        }
        #pragma unroll
        for (int l = 0; l < 4; ++l) {
            int gw = l * 256 + w * 64;
            int g  = gw + lane;
            int row = g >> 3;
            int c   = (g & 7) ^ (row & 7);
            gload16(gb + (size_t)row * KS + c * 8, Bs[bi] + gw * 8);
        }
    };

    auto compute = [&](int bi) {
        const _Float16* Ab = As[bi];
        const _Float16* Bb = Bs[bi];
        const int r16 = lane & 15;
        #pragma unroll
        for (int kh = 0; kh < 2; ++kh) {
            const int ks = (lane >> 4) + kh * 4;
            half8_t a[4], b[4];
            #pragma unroll
            for (int mi = 0; mi < 4; ++mi) {
                int row = wr + mi * 16 + r16;
                a[mi] = *(const half8_t*)(Ab + row * 64 + ((ks ^ (row & 7)) * 8));
            }
            #pragma unroll
            for (int ni = 0; ni < 4; ++ni) {
                int col = wc + ni * 16 + r16;
                b[ni] = *(const half8_t*)(Bb + col * 64 + ((ks ^ (col & 7)) * 8));
            }
            #pragma unroll
            for (int mi = 0; mi < 4; ++mi)
                #pragma unroll
                for (int ni = 0; ni < 4; ++ni)
                    acc[mi][ni] = __builtin_amdgcn_mfma_f32_16x16x32_f16(
                        a[mi], b[ni], acc[mi][ni], 0, 0, 0);
        }
    };

    stage(0, 0);          // 8 loads in flight
    stage(1, 1);          // 16 in flight
    int buf = 0;
    #pragma unroll 1
    for (int kt = 0; kt < NKT - 1; ++kt) {
        // counted wait: <=8 outstanding left => tile kt's 8 loads complete (in-order)
        asm volatile("s_waitcnt vmcnt(8)" ::: "memory");
        __builtin_amdgcn_s_barrier();     // all waves: tile kt ready; buf+2 free
        if (kt + 2 < NKT) {
            int bi2 = buf + 2; if (bi2 >= 3) bi2 -= 3;
            stage(kt + 2, bi2);
        }
        compute(buf);
        ++buf; if (buf == 3) buf = 0;
    }
    asm volatile("s_waitcnt vmcnt(0)" ::: "memory");
    __builtin_amdgcn_s_barrier();
    compute(buf);

    // C/D layout: col = lane&15, row = (lane>>4)*4 + q
    #pragma unroll
    for (int mi = 0; mi < 4; ++mi) {
        int r = row0 + wr + mi * 16 + (lane >> 4) * 4;
        #pragma unroll
        for (int ni = 0; ni < 4; ++ni) {
            int cidx = col0 + wc + ni * 16 + (lane & 15);
            float bv = BIAS ? bias[cidx] : 0.f;
            #pragma unroll
            for (int q = 0; q < 4; ++q)
                out[(size_t)(r + q) * HID + cidx] = acc[mi][ni][q] + bv;
        }
    }
}

// ---------------- LayerNorm + exact GELU, in-place on f32 ----------------
__global__ __launch_bounds__(256) void ln_gelu(float* __restrict__ h,
    const float* __restrict__ g, const float* __restrict__ bb)
{
    int row = blockIdx.x;
    int tid = threadIdx.x;
    float v0 = h[row*512 + tid];
    float v1 = h[row*512 + 256 + tid];
    __shared__ float red[4];
    int wid = tid >> 6, lane = tid & 63;

    float s = v0 + v1;
    #pragma unroll
    for (int off = 32; off; off >>= 1) s += __shfl_down(s, off);
    if (lane == 0) red[wid] = s;
    __syncthreads();
    float mu = (red[0]+red[1]+red[2]+red[3]) * (1.f/512.f);
    __syncthreads();

    float d0 = v0 - mu, d1 = v1 - mu;
    float q = d0*d0 + d1*d1;
    #pragma unroll
    for (int off = 32; off; off >>= 1) q += __shfl_down(q, off);
    if (lane == 0) red[wid] = q;
    __syncthreads();
    float var = (red[0]+red[1]+red[2]+red[3]) * (1.f/512.f);
    float rs = rsqrtf(var + 1e-5f);

    float y0 = d0*rs*g[tid] + bb[tid];
    float y1 = d1*rs*g[tid+256] + bb[tid+256];
    y0 = 0.5f*y0*(1.f + erff(y0*0.70710678118654752f));
    y1 = 0.5f*y1*(1.f + erff(y1*0.70710678118654752f));
    h[row*512 + tid] = y0;
    h[row*512 + 256 + tid] = y1;
}

// ---------------- XT[b][h][n] = f16(x[b][n][h]) ----------------
__global__ __launch_bounds__(256) void transpose_x(const float* __restrict__ x,
    _Float16* __restrict__ XT)
{
    __shared__ _Float16 ts[64][68];   // [n in tile][h in tile]
    int b = blockIdx.z;
    int n0 = blockIdx.y * 64, h0 = blockIdx.x * 64;  // grid (8, 4, 32)
    int tid = threadIdx.x;
    int r = tid >> 2, q = tid & 3;
    const float* xp = x + ((size_t)(b*NSEQ + n0 + r)) * HID + h0 + q * 16;
    #pragma unroll
    for (int i = 0; i < 4; ++i) {
        float4 v = *(const float4*)(xp + i * 4);
        ts[r][q*16 + i*4 + 0] = (_Float16)v.x;
        ts[r][q*16 + i*4 + 1] = (_Float16)v.y;
        ts[r][q*16 + i*4 + 2] = (_Float16)v.z;
        ts[r][q*16 + i*4 + 3] = (_Float16)v.w;
    }
    __syncthreads();
    _Float16* op = XT + (size_t)b*(HID*NSEQ) + (size_t)(h0 + r)*NSEQ + n0 + q*16;
    #pragma unroll
    for (int i = 0; i < 4; ++i) {
        half4_t o;
        #pragma unroll
        for (int j = 0; j < 4; ++j) o[j] = ts[q*16 + i*4 + j][r];
        *(half4_t*)(op + i * 4) = o;
    }
}

// ---------------- C16[b][t][n][m] = f16( (adj>=1 ? V[adj][t] : 0) + (n==m)*V[0][t] ) ----
__global__ __launch_bounds__(256) void buildC(const int* __restrict__ adj,
    const float* __restrict__ V, _Float16* __restrict__ C16)
{
    __shared__ float lut[16][3];
    __shared__ float V0[3];
    int tid = threadIdx.x;
    if (tid < 48) { int r = tid / 3, c = tid - r * 3; lut[r][c] = (r >= 1) ? V[tid] : 0.f; }
    if (tid < 3) V0[tid] = V[tid];
    __syncthreads();
    int b = blockIdx.y;
    int n = blockIdx.x * 64 + (tid >> 2), mq = tid & 3;   // grid (4, 32)
    const int* ap = adj + ((size_t)(b*NSEQ + n)) * NSEQ + mq * 64;
    size_t obase = ((size_t)(b*3) << 16) + (size_t)n * 256 + mq * 64;
    #pragma unroll
    for (int i = 0; i < 16; ++i) {
        int4 a4 = *(const int4*)(ap + i * 4);
        int av[4] = { a4.x, a4.y, a4.z, a4.w };
        #pragma unroll
        for (int t = 0; t < 3; ++t) {
            half4_t o;
            #pragma unroll
            for (int j = 0; j < 4; ++j) {
                int m = mq * 64 + i * 4 + j;
                float v = lut[av[j]][t] + ((m == n) ? V0[t] : 0.f);
                o[j] = (_Float16)v;
            }
            *(half4_t*)(C16 + obase + ((size_t)t << 16) + i * 4) = o;
        }
    }
}

// ---------------- agg: Z_t[b] = C16[b][t] @ X[b]  (M=256 n, N=512 h, K=256 m) --------
__global__ __launch_bounds__(256) void agg_mfma(
    const _Float16* __restrict__ C16, const _Float16* __restrict__ XT,
    _Float16* __restrict__ z)
{
    __shared__ _Float16 smem[32768];   // 64KB: As0|As1|Bs0|Bs1 (8192 f16 each)
    const int tid = threadIdx.x;
    const int w = tid >> 6, lane = tid & 63;
    const int bz = blockIdx.z;                 // b*3 + trel
    const int b = bz / 3, trel = bz - b * 3;
    const int n0 = blockIdx.y * 128, h0 = blockIdx.x * 128;  // grid (4, 2, 96)
    const int wr = (w >> 1) * 64, wc = (w & 1) * 64;
    const _Float16* Ag = C16 + ((size_t)bz << 16) + (size_t)n0 * 256;
    const _Float16* Bg = XT + (size_t)b * (HID*NSEQ) + (size_t)h0 * 256;

    f32x4 acc[4][4] = {};

    auto stage = [&](const _Float16* gbase, _Float16* lds) {
        #pragma unroll
        for (int l = 0; l < 4; ++l) {
            int gw = l * 256 + w * 64;
            int g  = gw + lane;
            int row = g >> 3;
            int c   = (g & 7) ^ (row & 7);
            gload16(gbase + (size_t)row * 256 + c * 8, lds + (size_t)gw * 8);
        }
    };

    stage(Ag, smem);            // As0
    stage(Bg, smem + 16384);    // Bs0
    asm volatile("s_waitcnt vmcnt(0)" ::: "memory");
    __syncthreads();

    int buf = 0;
    for (int kt = 0; kt < 4; ++kt) {
        if (kt < 3) {
            stage(Ag + (kt + 1) * 64, smem + (buf ^ 1) * 8192);
            stage(Bg + (kt + 1) * 64, smem + 16384 + (buf ^ 1) * 8192);
        }
        const _Float16* Ab = smem + buf * 8192;
        const _Float16* Bb = smem + 16384 + buf * 8192;
        const int r16 = lane & 15;
        #pragma unroll
        for (int kh = 0; kh < 2; ++kh) {
            const int ks = (lane >> 4) + kh * 4;
            half8_t a[4], bf[4];
            #pragma unroll
            for (int mi = 0; mi < 4; ++mi) {
                int row = wr + mi * 16 + r16;
                a[mi] = *(const half8_t*)(Ab + row * 64 + ((ks ^ (row & 7)) * 8));
            }
            #pragma unroll
            for (int ni = 0; ni < 4; ++ni) {
                int col = wc + ni * 16 + r16;
                bf[ni] = *(const half8_t*)(Bb + col * 64 + ((ks ^ (col & 7)) * 8));
            }
            #pragma unroll
            for (int mi = 0; mi < 4; ++mi)
                #pragma unroll
                for (int ni = 0; ni < 4; ++ni)
                    acc[mi][ni] = __builtin_amdgcn_mfma_f32_16x16x32_f16(
                        a[mi], bf[ni], acc[mi][ni], 0, 0, 0);
        }
        if (kt < 3) asm volatile("s_waitcnt vmcnt(0)" ::: "memory");
        __syncthreads();
        buf ^= 1;
    }

    // repack acc -> smem[0..16384) as [128 n][128 h] f16 (safe: barrier passed)
    #pragma unroll
    for (int mi = 0; mi < 4; ++mi) {
        int rbase = wr + mi * 16 + (lane >> 4) * 4;
        #pragma unroll
        for (int ni = 0; ni < 4; ++ni) {
            int col = wc + ni * 16 + (lane & 15);
            #pragma unroll
            for (int q = 0; q < 4; ++q)
                smem[(rbase + q) * 128 + col] = (_Float16)acc[mi][ni][q];
        }
    }
    __syncthreads();

    // coalesced copy: 2048 granules of 16B
    _Float16* zb = z + ((size_t)(b*NSEQ + n0)) * KTOT + trel * 512 + h0;
    #pragma unroll
    for (int i = 0; i < 8; ++i) {
        int g = i * 256 + tid;
        int row = g >> 4, hoff = (g & 15) * 8;
        *(half8_t*)(zb + (size_t)row * KTOT + hoff) = *(const half8_t*)(smem + g * 8);
    }
}

extern "C" void kernel_launch(void* const* d_in, const int* in_sizes, int n_in,
                              void* d_out, int out_size, void* d_ws, size_t ws_size,
                              hipStream_t stream)
{
    const float* cols   = (const float*)d_in[0];
    const float* logits = (const float*)d_in[1];
    const int*   adj    = (const int*)  d_in[2];
    const float* Wp     = (const float*)d_in[3];
    const float* bp     = (const float*)d_in[4];
    const float* lg     = (const float*)d_in[5];
    const float* lb     = (const float*)d_in[6];
    const float* W      = (const float*)d_in[7];
    const float* V      = (const float*)d_in[8];
    float* out  = (float*)d_out;

    float* xbuf = (float*)d_ws;                                       // 16.8 MB
    char* p = (char*)d_ws + (size_t)ROWS*HID*4;
    _Float16* zbuf = (_Float16*)p;  p += (size_t)ROWS*KTOT*2;         // 25.2 MB
    _Float16* Whc  = (_Float16*)p;  p += (size_t)HID*KTOT*2;          // 1.6 MB
    _Float16* XT   = (_Float16*)p;  p += (size_t)BSZ*HID*NSEQ*2;      // 8.4 MB
    _Float16* C16  = (_Float16*)p;  p += (size_t)BSZ*3*NSEQ*NSEQ*2;   // 12.6 MB
    _Float16* Acat = (_Float16*)p;  p += (size_t)ROWS*KP*2;           // 9.4 MB
    _Float16* WpT  = (_Float16*)p;                                    // 0.6 MB

    convW      <<<dim3(6,512), 256, 0, stream>>>(W, Whc);
    cat_inp    <<<dim3(ROWS), 256, 0, stream>>>(cols, logits, Acat);
    transW     <<<dim3(9,8), 256, 0, stream>>>(Wp, WpT);
    gemm_f16p<KP,9,true><<<dim3(4,64), 256, 0, stream>>>(Acat, WpT, bp, xbuf);
    ln_gelu    <<<ROWS, 256, 0, stream>>>(xbuf, lg, lb);
    transpose_x<<<dim3(8,4,32), 256, 0, stream>>>(xbuf, XT);
    buildC     <<<dim3(4,32), 256, 0, stream>>>(adj, V, C16);
    agg_mfma   <<<dim3(4,2,96), 256, 0, stream>>>(C16, XT, zbuf);
    gemm_f16p<KTOT,24,false><<<dim3(4,64), 256, 0, stream>>>(zbuf, Whc, nullptr, out);
}

// Round 5
// 102.763 us; speedup vs baseline: 3.6491x; 1.0869x over previous
//
#include <hip/hip_runtime.h>
#include <math.h>

#define HID 512
#define NSEQ 256
#define BSZ 32
#define ROWS (BSZ*NSEQ)   // 8192
#define KTOT 1536
#define KP 576            // padded proj K (514 -> 576 = 9*64)

typedef _Float16 half8_t __attribute__((ext_vector_type(8)));
typedef _Float16 half4_t __attribute__((ext_vector_type(4)));
typedef float f32x4 __attribute__((ext_vector_type(4)));

__device__ __forceinline__ void gload16(const _Float16* g, _Float16* l) {
    __builtin_amdgcn_global_load_lds(
        (const __attribute__((address_space(1))) unsigned int*)g,
        (__attribute__((address_space(3))) unsigned int*)l, 16, 0, 0);
}

// ---------------- Whc[o][k] = f16(W[h][t][o]), k = t*512+h ----------------
__global__ __launch_bounds__(256) void convW(const float* __restrict__ W,
                                             _Float16* __restrict__ Whc)
{
    int k = blockIdx.x * 256 + threadIdx.x;   // grid.x = 6
    int o = blockIdx.y;                        // 512
    int h = k & 511, t = k >> 9;
    Whc[(size_t)o * KTOT + k] = (_Float16)W[(size_t)h * KTOT + t * 512 + o];
}

// ---------------- Acat[row][k] = f16 concat(columns,logits), zero pad to KP --------
__global__ __launch_bounds__(256) void cat_inp(const float* __restrict__ cols,
    const float* __restrict__ logits, _Float16* __restrict__ Acat)
{
    int row = blockIdx.x;
    for (int k = threadIdx.x; k < KP; k += 256) {
        float v = 0.f;
        if (k < 512) v = cols[(size_t)row * 512 + k];
        else if (k < 514) v = logits[(size_t)row * 2 + (k - 512)];
        Acat[(size_t)row * KP + k] = (_Float16)v;
    }
}

// ---------------- WpT[o][k] = f16(Wp[k][o]), k padded 514->KP with zeros ----------
__global__ __launch_bounds__(256) void transW(const float* __restrict__ Wp,
                                              _Float16* __restrict__ WpT)
{
    __shared__ _Float16 ts[64][68];   // [k in tile][o in tile]
    int k0 = blockIdx.x * 64, o0 = blockIdx.y * 64;  // grid (9, 8)
    int tid = threadIdx.x;
    int r = tid >> 2, q = tid & 3;
    int k = k0 + r;
    #pragma unroll
    for (int i = 0; i < 4; ++i) {
        float4 v = make_float4(0.f, 0.f, 0.f, 0.f);
        if (k < 514) v = *(const float4*)&Wp[(size_t)k * HID + o0 + q * 16 + i * 4];
        ts[r][q*16 + i*4 + 0] = (_Float16)v.x;
        ts[r][q*16 + i*4 + 1] = (_Float16)v.y;
        ts[r][q*16 + i*4 + 2] = (_Float16)v.z;
        ts[r][q*16 + i*4 + 3] = (_Float16)v.w;
    }
    __syncthreads();
    _Float16* op = WpT + (size_t)(o0 + r) * KP + k0 + q * 16;
    #pragma unroll
    for (int i = 0; i < 4; ++i) {
        half4_t o;
        #pragma unroll
        for (int j = 0; j < 4; ++j) o[j] = ts[q*16 + i*4 + j][r];
        *(half4_t*)(op + i * 4) = o;
    }
}

// ------- 128x128 f16 MFMA GEMM, 512 thr / 8 waves, 3-deep counted-vmcnt pipeline -------
// A[M][KS], B[N][KS], out f32 [M][512]. Grid (4, M/128). Wave tile 64x32.
// 4 gloads/wave/tile. XCD-chunked block swizzle.
template<int KS, int NKT, bool BIAS>
__global__ __launch_bounds__(512) void gemm512(
    const _Float16* __restrict__ A, const _Float16* __restrict__ Bm,
    const float* __restrict__ bias, float* __restrict__ out)
{
    __shared__ _Float16 As[3][128*64];   // 48KB
    __shared__ _Float16 Bs[3][128*64];   // 48KB
    const int tid = threadIdx.x;
    const int w = tid >> 6, lane = tid & 63;
    // XCD swizzle: linear id -> chunked so 4 col-blocks of one row-panel share an XCD
    const int ell = blockIdx.y * 4 + blockIdx.x;      // HW dispatch order (x-major)
    const int s   = (ell & 7) * 32 + (ell >> 3);      // 256 blocks, 8 XCDs, 32/XCD
    const int row0 = (s >> 2) * 128, col0 = (s & 3) * 128;
    const int wr = (w >> 2) * 64, wc = (w & 3) * 32;
    const _Float16* Ag = A  + (size_t)row0 * KS;
    const _Float16* Bg = Bm + (size_t)col0 * KS;

    f32x4 acc[4][2] = {};

    // stage tile kt into buffer bi. LDS dest linear; global source pre-swizzled:
    // physical granule (row, c) holds logical (row, c ^ (row&7)).
    auto stage = [&](int kt, int bi) {
        const _Float16* ga = Ag + kt * 64;
        const _Float16* gb = Bg + kt * 64;
        #pragma unroll
        for (int l = 0; l < 2; ++l) {
            int gw = w * 128 + l * 64;
            int g  = gw + lane;
            int row = g >> 3;
            int c   = (g & 7) ^ (row & 7);
            gload16(ga + (size_t)row * KS + c * 8, As[bi] + gw * 8);
        }
        #pragma unroll
        for (int l = 0; l < 2; ++l) {
            int gw = w * 128 + l * 64;
            int g  = gw + lane;
            int row = g >> 3;
            int c   = (g & 7) ^ (row & 7);
            gload16(gb + (size_t)row * KS + c * 8, Bs[bi] + gw * 8);
        }
    };

    auto compute = [&](int bi) {
        const _Float16* Ab = As[bi];
        const _Float16* Bb = Bs[bi];
        const int r16 = lane & 15;
        #pragma unroll
        for (int kh = 0; kh < 2; ++kh) {
            const int ks = (lane >> 4) + kh * 4;
            half8_t a[4], b[2];
            #pragma unroll
            for (int mi = 0; mi < 4; ++mi) {
                int row = wr + mi * 16 + r16;
                a[mi] = *(const half8_t*)(Ab + row * 64 + ((ks ^ (row & 7)) * 8));
            }
            #pragma unroll
            for (int ni = 0; ni < 2; ++ni) {
                int col = wc + ni * 16 + r16;
                b[ni] = *(const half8_t*)(Bb + col * 64 + ((ks ^ (col & 7)) * 8));
            }
            #pragma unroll
            for (int mi = 0; mi < 4; ++mi)
                #pragma unroll
                for (int ni = 0; ni < 2; ++ni)
                    acc[mi][ni] = __builtin_amdgcn_mfma_f32_16x16x32_f16(
                        a[mi], b[ni], acc[mi][ni], 0, 0, 0);
        }
    };

    stage(0, 0);          // 4/wave in flight
    stage(1, 1);          // 8/wave in flight
    int buf = 0;
    #pragma unroll 1
    for (int kt = 0; kt < NKT - 1; ++kt) {
        // <=4 outstanding => tile kt's 4 loads complete (in-order per wave)
        asm volatile("s_waitcnt vmcnt(4)" ::: "memory");
        __builtin_amdgcn_s_barrier();
        if (kt + 2 < NKT) {
            int bi2 = buf + 2; if (bi2 >= 3) bi2 -= 3;
            stage(kt + 2, bi2);
        }
        compute(buf);
        ++buf; if (buf == 3) buf = 0;
    }
    asm volatile("s_waitcnt vmcnt(0)" ::: "memory");
    __builtin_amdgcn_s_barrier();
    compute(buf);

    // C/D layout: col = lane&15, row = (lane>>4)*4 + q
    #pragma unroll
    for (int mi = 0; mi < 4; ++mi) {
        int r = row0 + wr + mi * 16 + (lane >> 4) * 4;
        #pragma unroll
        for (int ni = 0; ni < 2; ++ni) {
            int cidx = col0 + wc + ni * 16 + (lane & 15);
            float bv = BIAS ? bias[cidx] : 0.f;
            #pragma unroll
            for (int q = 0; q < 4; ++q)
                out[(size_t)(r + q) * HID + cidx] = acc[mi][ni][q] + bv;
        }
    }
}

// ------------- LayerNorm + exact GELU: read f32, write f16 row-major -------------
__global__ __launch_bounds__(256) void ln_gelu_f16(const float* __restrict__ h,
    const float* __restrict__ g, const float* __restrict__ bb,
    _Float16* __restrict__ xrm)
{
    int row = blockIdx.x;
    int tid = threadIdx.x;
    float v0 = h[row*512 + tid];
    float v1 = h[row*512 + 256 + tid];
    __shared__ float red[4];
    int wid = tid >> 6, lane = tid & 63;

    float s = v0 + v1;
    #pragma unroll
    for (int off = 32; off; off >>= 1) s += __shfl_down(s, off);
    if (lane == 0) red[wid] = s;
    __syncthreads();
    float mu = (red[0]+red[1]+red[2]+red[3]) * (1.f/512.f);
    __syncthreads();

    float d0 = v0 - mu, d1 = v1 - mu;
    float q = d0*d0 + d1*d1;
    #pragma unroll
    for (int off = 32; off; off >>= 1) q += __shfl_down(q, off);
    if (lane == 0) red[wid] = q;
    __syncthreads();
    float var = (red[0]+red[1]+red[2]+red[3]) * (1.f/512.f);
    float rs = rsqrtf(var + 1e-5f);

    float y0 = d0*rs*g[tid] + bb[tid];
    float y1 = d1*rs*g[tid+256] + bb[tid+256];
    y0 = 0.5f*y0*(1.f + erff(y0*0.70710678118654752f));
    y1 = 0.5f*y1*(1.f + erff(y1*0.70710678118654752f));
    xrm[(size_t)row*512 + tid]       = (_Float16)y0;
    xrm[(size_t)row*512 + 256 + tid] = (_Float16)y1;
}

// ---------------- XT[b][h][n] = xrm[b][n][h] (f16 -> f16 transpose) ----------------
__global__ __launch_bounds__(256) void transpose_x16(const _Float16* __restrict__ xrm,
    _Float16* __restrict__ XT)
{
    __shared__ _Float16 ts[64][72];
    int b = blockIdx.z;
    int n0 = blockIdx.y * 64, h0 = blockIdx.x * 64;  // grid (8, 4, 32)
    int tid = threadIdx.x;
    int r = tid >> 2, q = tid & 3;
    const _Float16* xp = xrm + ((size_t)(b*NSEQ + n0 + r)) * HID + h0 + q * 16;
    *(half8_t*)&ts[r][q*16]     = *(const half8_t*)(xp);
    *(half8_t*)&ts[r][q*16 + 8] = *(const half8_t*)(xp + 8);
    __syncthreads();
    _Float16* op = XT + (size_t)b*(HID*NSEQ) + (size_t)(h0 + r)*NSEQ + n0 + q*16;
    half8_t o0, o1;
    #pragma unroll
    for (int j = 0; j < 8; ++j) { o0[j] = ts[q*16 + j][r]; o1[j] = ts[q*16 + 8 + j][r]; }
    *(half8_t*)(op)     = o0;
    *(half8_t*)(op + 8) = o1;
}

// ---------------- C16[b][t][n][m] = f16( (adj>=1 ? V[adj][t] : 0) + (n==m)*V[0][t] ) ----
__global__ __launch_bounds__(256) void buildC(const int* __restrict__ adj,
    const float* __restrict__ V, _Float16* __restrict__ C16)
{
    __shared__ float lut[16][3];
    __shared__ float V0[3];
    int tid = threadIdx.x;
    if (tid < 48) { int r = tid / 3, c = tid - r * 3; lut[r][c] = (r >= 1) ? V[tid] : 0.f; }
    if (tid < 3) V0[tid] = V[tid];
    __syncthreads();
    int b = blockIdx.y;
    int n = blockIdx.x * 64 + (tid >> 2), mq = tid & 3;   // grid (4, 32)
    const int* ap = adj + ((size_t)(b*NSEQ + n)) * NSEQ + mq * 64;
    size_t obase = ((size_t)(b*3) << 16) + (size_t)n * 256 + mq * 64;
    #pragma unroll
    for (int i = 0; i < 16; ++i) {
        int4 a4 = *(const int4*)(ap + i * 4);
        int av[4] = { a4.x, a4.y, a4.z, a4.w };
        #pragma unroll
        for (int t = 0; t < 3; ++t) {
            half4_t o;
            #pragma unroll
            for (int j = 0; j < 4; ++j) {
                int m = mq * 64 + i * 4 + j;
                float v = lut[av[j]][t] + ((m == n) ? V0[t] : 0.f);
                o[j] = (_Float16)v;
            }
            *(half4_t*)(C16 + obase + ((size_t)t << 16) + i * 4) = o;
        }
    }
}

// ---------------- agg: Z_t[b] = C16[b][t] @ X[b]  (M=256 n, N=512 h, K=256 m) --------
__global__ __launch_bounds__(256) void agg_mfma(
    const _Float16* __restrict__ C16, const _Float16* __restrict__ XT,
    _Float16* __restrict__ z)
{
    __shared__ _Float16 smem[32768];   // 64KB: As0|As1|Bs0|Bs1 (8192 f16 each)
    const int tid = threadIdx.x;
    const int w = tid >> 6, lane = tid & 63;
    const int bz = blockIdx.z;                 // b*3 + trel
    const int b = bz / 3, trel = bz - b * 3;
    const int n0 = blockIdx.y * 128, h0 = blockIdx.x * 128;  // grid (4, 2, 96)
    const int wr = (w >> 1) * 64, wc = (w & 1) * 64;
    const _Float16* Ag = C16 + ((size_t)bz << 16) + (size_t)n0 * 256;
    const _Float16* Bg = XT + (size_t)b * (HID*NSEQ) + (size_t)h0 * 256;

    f32x4 acc[4][4] = {};

    auto stage = [&](const _Float16* gbase, _Float16* lds) {
        #pragma unroll
        for (int l = 0; l < 4; ++l) {
            int gw = l * 256 + w * 64;
            int g  = gw + lane;
            int row = g >> 3;
            int c   = (g & 7) ^ (row & 7);
            gload16(gbase + (size_t)row * 256 + c * 8, lds + (size_t)gw * 8);
        }
    };

    stage(Ag, smem);            // As0
    stage(Bg, smem + 16384);    // Bs0
    asm volatile("s_waitcnt vmcnt(0)" ::: "memory");
    __syncthreads();

    int buf = 0;
    for (int kt = 0; kt < 4; ++kt) {
        if (kt < 3) {
            stage(Ag + (kt + 1) * 64, smem + (buf ^ 1) * 8192);
            stage(Bg + (kt + 1) * 64, smem + 16384 + (buf ^ 1) * 8192);
        }
        const _Float16* Ab = smem + buf * 8192;
        const _Float16* Bb = smem + 16384 + buf * 8192;
        const int r16 = lane & 15;
        #pragma unroll
        for (int kh = 0; kh < 2; ++kh) {
            const int ks = (lane >> 4) + kh * 4;
            half8_t a[4], bf[4];
            #pragma unroll
            for (int mi = 0; mi < 4; ++mi) {
                int row = wr + mi * 16 + r16;
                a[mi] = *(const half8_t*)(Ab + row * 64 + ((ks ^ (row & 7)) * 8));
            }
            #pragma unroll
            for (int ni = 0; ni < 4; ++ni) {
                int col = wc + ni * 16 + r16;
                bf[ni] = *(const half8_t*)(Bb + col * 64 + ((ks ^ (col & 7)) * 8));
            }
            #pragma unroll
            for (int mi = 0; mi < 4; ++mi)
                #pragma unroll
                for (int ni = 0; ni < 4; ++ni)
                    acc[mi][ni] = __builtin_amdgcn_mfma_f32_16x16x32_f16(
                        a[mi], bf[ni], acc[mi][ni], 0, 0, 0);
        }
        if (kt < 3) asm volatile("s_waitcnt vmcnt(0)" ::: "memory");
        __syncthreads();
        buf ^= 1;
    }

    // repack acc -> smem[0..16384) as [128 n][128 h] f16 (safe: barrier passed)
    #pragma unroll
    for (int mi = 0; mi < 4; ++mi) {
        int rbase = wr + mi * 16 + (lane >> 4) * 4;
        #pragma unroll
        for (int ni = 0; ni < 4; ++ni) {
            int col = wc + ni * 16 + (lane & 15);
            #pragma unroll
            for (int q = 0; q < 4; ++q)
                smem[(rbase + q) * 128 + col] = (_Float16)acc[mi][ni][q];
        }
    }
    __syncthreads();

    // coalesced copy: 2048 granules of 16B
    _Float16* zb = z + ((size_t)(b*NSEQ + n0)) * KTOT + trel * 512 + h0;
    #pragma unroll
    for (int i = 0; i < 8; ++i) {
        int g = i * 256 + tid;
        int row = g >> 4, hoff = (g & 15) * 8;
        *(half8_t*)(zb + (size_t)row * KTOT + hoff) = *(const half8_t*)(smem + g * 8);
    }
}

extern "C" void kernel_launch(void* const* d_in, const int* in_sizes, int n_in,
                              void* d_out, int out_size, void* d_ws, size_t ws_size,
                              hipStream_t stream)
{
    const float* cols   = (const float*)d_in[0];
    const float* logits = (const float*)d_in[1];
    const int*   adj    = (const int*)  d_in[2];
    const float* Wp     = (const float*)d_in[3];
    const float* bp     = (const float*)d_in[4];
    const float* lg     = (const float*)d_in[5];
    const float* lb     = (const float*)d_in[6];
    const float* W      = (const float*)d_in[7];
    const float* V      = (const float*)d_in[8];
    float* out  = (float*)d_out;

    float* xbuf = (float*)d_ws;                                       // 16.8 MB
    char* p = (char*)d_ws + (size_t)ROWS*HID*4;
    _Float16* zbuf = (_Float16*)p;  p += (size_t)ROWS*KTOT*2;         // 25.2 MB
    _Float16* Whc  = (_Float16*)p;  p += (size_t)HID*KTOT*2;          // 1.6 MB
    _Float16* XT   = (_Float16*)p;  p += (size_t)BSZ*HID*NSEQ*2;      // 8.4 MB
    _Float16* C16  = (_Float16*)p;  p += (size_t)BSZ*3*NSEQ*NSEQ*2;   // 12.6 MB
    _Float16* Acat = (_Float16*)p;  p += (size_t)ROWS*KP*2;           // 9.4 MB
    _Float16* WpT  = (_Float16*)p;                                    // 0.6 MB
    _Float16* Xrm  = Acat;   // reuse: Acat dead after proj GEMM; 8.4 MB <= 9.4 MB

    convW      <<<dim3(6,512), 256, 0, stream>>>(W, Whc);
    cat_inp    <<<dim3(ROWS), 256, 0, stream>>>(cols, logits, Acat);
    transW     <<<dim3(9,8), 256, 0, stream>>>(Wp, WpT);
    gemm512<KP,9,true><<<dim3(4,64), 512, 0, stream>>>(Acat, WpT, bp, xbuf);
    ln_gelu_f16<<<ROWS, 256, 0, stream>>>(xbuf, lg, lb, Xrm);
    transpose_x16<<<dim3(8,4,32), 256, 0, stream>>>(Xrm, XT);
    buildC     <<<dim3(4,32), 256, 0, stream>>>(adj, V, C16);
    agg_mfma   <<<dim3(4,2,96), 256, 0, stream>>>(C16, XT, zbuf);
    gemm512<KTOT,24,false><<<dim3(4,64), 512, 0, stream>>>(zbuf, Whc, nullptr, out);
}

// Round 6
// 83.751 us; speedup vs baseline: 4.4775x; 1.2270x over previous
//
#include <hip/hip_runtime.h>
#include <math.h>

#define HID 512
#define NSEQ 256
#define BSZ 32
#define ROWS (BSZ*NSEQ)   // 8192
#define KP 576            // padded proj K (514 -> 576 = 9*64)

typedef _Float16 half8_t __attribute__((ext_vector_type(8)));
typedef _Float16 half4_t __attribute__((ext_vector_type(4)));
typedef float f32x4 __attribute__((ext_vector_type(4)));

__device__ __forceinline__ void gload16(const _Float16* g, _Float16* l) {
    __builtin_amdgcn_global_load_lds(
        (const __attribute__((address_space(1))) unsigned int*)g,
        (__attribute__((address_space(3))) unsigned int*)l, 16, 0, 0);
}

// =============== fused prep: cat_inp | WcT transpose | WpT transpose | buildC ========
// WcT[c][h]  = f16(W[h*1536 + c])            c = t*512+o   [1536][512]
// WpT[o][k]  = f16(Wp[k][o]) zero-pad k>=514                [512][576]
// C16b[(b*256+n)][t*256+m] = f16( lut[adj[b,n,m]][t] + (n==m)*V[0][t] )
__global__ __launch_bounds__(256) void prep(
    const float* __restrict__ cols, const float* __restrict__ logits,
    const float* __restrict__ Wp, const float* __restrict__ W,
    const int* __restrict__ adj, const float* __restrict__ V,
    _Float16* __restrict__ Acat, _Float16* __restrict__ WpT,
    _Float16* __restrict__ WcT, _Float16* __restrict__ C16b)
{
    __shared__ _Float16 ts[64][68];
    __shared__ float lut[16][3];
    __shared__ float V0s[3];
    const int blk = blockIdx.x, tid = threadIdx.x;

    if (blk < 8192) {                       // ---- Acat: concat+cast, pad to 576
        int row = blk;
        for (int k = tid; k < KP; k += 256) {
            float v = 0.f;
            if (k < 512) v = cols[(size_t)row*512 + k];
            else if (k < 514) v = logits[(size_t)row*2 + (k-512)];
            Acat[(size_t)row*KP + k] = (_Float16)v;
        }
    } else if (blk < 8384) {                // ---- WcT (192 blocks: 24 c-tiles x 8 h-tiles)
        int sub = blk - 8192;
        int c0 = (sub % 24) * 64, h0 = (sub / 24) * 64;
        int r = tid >> 2, q = tid & 3;
        #pragma unroll
        for (int i = 0; i < 4; ++i) {
            float4 v = *(const float4*)&W[(size_t)(h0+r)*1536 + c0 + q*16 + i*4];
            ts[r][q*16+i*4+0] = (_Float16)v.x;
            ts[r][q*16+i*4+1] = (_Float16)v.y;
            ts[r][q*16+i*4+2] = (_Float16)v.z;
            ts[r][q*16+i*4+3] = (_Float16)v.w;
        }
        __syncthreads();
        _Float16* op = WcT + (size_t)(c0 + r)*512 + h0 + q*16;
        #pragma unroll
        for (int i = 0; i < 4; ++i) {
            half4_t o;
            #pragma unroll
            for (int j = 0; j < 4; ++j) o[j] = ts[q*16+i*4+j][r];
            *(half4_t*)(op + i*4) = o;
        }
    } else if (blk < 8456) {                // ---- WpT (72 blocks: 9 k-tiles x 8 o-tiles)
        int sub = blk - 8384;
        int k0 = (sub % 9) * 64, o0 = (sub / 9) * 64;
        int r = tid >> 2, q = tid & 3;
        int k = k0 + r;
        #pragma unroll
        for (int i = 0; i < 4; ++i) {
            float4 v = make_float4(0.f,0.f,0.f,0.f);
            if (k < 514) v = *(const float4*)&Wp[(size_t)k*HID + o0 + q*16 + i*4];
            ts[r][q*16+i*4+0] = (_Float16)v.x;
            ts[r][q*16+i*4+1] = (_Float16)v.y;
            ts[r][q*16+i*4+2] = (_Float16)v.z;
            ts[r][q*16+i*4+3] = (_Float16)v.w;
        }
        __syncthreads();
        _Float16* op = WpT + (size_t)(o0 + r)*KP + k0 + q*16;
        #pragma unroll
        for (int i = 0; i < 4; ++i) {
            half4_t o;
            #pragma unroll
            for (int j = 0; j < 4; ++j) o[j] = ts[q*16+i*4+j][r];
            *(half4_t*)(op + i*4) = o;
        }
    } else {                                // ---- C16b (128 blocks: 32 b x 4 n-tiles)
        if (tid < 48) { int r = tid/3, c = tid - r*3; lut[r][c] = (r >= 1) ? V[tid] : 0.f; }
        if (tid < 3) V0s[tid] = V[tid];
        __syncthreads();
        int sub = blk - 8456;
        int b = sub >> 2, nt = sub & 3;
        int n = nt*64 + (tid >> 2), mq = tid & 3;
        const int* ap = adj + ((size_t)(b*NSEQ + n))*NSEQ + mq*64;
        size_t ob = ((size_t)(b*NSEQ + n))*768 + mq*64;
        #pragma unroll
        for (int i = 0; i < 16; ++i) {
            int4 a4 = *(const int4*)(ap + i*4);
            int av[4] = { a4.x, a4.y, a4.z, a4.w };
            #pragma unroll
            for (int t = 0; t < 3; ++t) {
                half4_t o;
                #pragma unroll
                for (int j = 0; j < 4; ++j) {
                    int m = mq*64 + i*4 + j;
                    float v = lut[av[j]][t] + ((m == n) ? V0s[t] : 0.f);
                    o[j] = (_Float16)v;
                }
                *(half4_t*)(C16b + ob + (size_t)t*256 + i*4) = o;
            }
        }
    }
}

// ====== unified 128x128 f16 MFMA GEMM, 512 thr / 8 waves (wave tile 64x32) ======
// A[M][KS], B[.][KS]. EPI: 0 = f32 out[r][512]+bias (proj)
//                          1 = f16 transposed scatter -> YT[b][o][t*256+m] (Y-GEMM)
//                          2 = f32 out[r][512], B base per b = row0>>8 (agg-out)
// DEPTH: 3 = counted-vmcnt 3-deep (96KB LDS); 2 = 2-phase dbuf (64KB LDS)
template<int KS, int NKT, int DEPTH, int NB, int NBLK, int EPI>
__global__ __launch_bounds__(512) void gemm512(
    const _Float16* __restrict__ A, const _Float16* __restrict__ Bm,
    const float* __restrict__ bias, void* __restrict__ outv)
{
    __shared__ _Float16 smem[DEPTH * 2 * 8192];
    _Float16* As = smem;
    _Float16* Bs = smem + DEPTH * 8192;
    const int tid = threadIdx.x;
    const int w = tid >> 6, lane = tid & 63;
    // XCD-chunked swizzle (NB % 8 == 0)
    const int ell = blockIdx.x;
    const int s = (ell & 7) * (NB / 8) + (ell >> 3);
    const int row0 = (s / NBLK) * 128, col0 = (s % NBLK) * 128;
    const int wr = (w >> 2) * 64, wc = (w & 3) * 32;
    const _Float16* Ag = A + (size_t)row0 * KS;
    const _Float16* Bg = (EPI == 2)
        ? Bm + (size_t)(row0 >> 8) * 512 * KS + (size_t)col0 * KS
        : Bm + (size_t)col0 * KS;

    f32x4 acc[4][2] = {};

    // stage tile kt into buffer bi. LDS dest linear; global source pre-swizzled:
    // physical granule (row, c) holds logical (row, c ^ (row&7)).
    auto stage = [&](int kt, int bi) {
        const _Float16* ga = Ag + kt * 64;
        const _Float16* gb = Bg + kt * 64;
        _Float16* la = As + bi * 8192;
        _Float16* lb = Bs + bi * 8192;
        #pragma unroll
        for (int l = 0; l < 2; ++l) {
            int gw = w * 128 + l * 64;
            int g  = gw + lane;
            int row = g >> 3;
            int c   = (g & 7) ^ (row & 7);
            gload16(ga + (size_t)row * KS + c * 8, la + gw * 8);
        }
        #pragma unroll
        for (int l = 0; l < 2; ++l) {
            int gw = w * 128 + l * 64;
            int g  = gw + lane;
            int row = g >> 3;
            int c   = (g & 7) ^ (row & 7);
            gload16(gb + (size_t)row * KS + c * 8, lb + gw * 8);
        }
    };

    auto compute = [&](int bi) {
        const _Float16* Ab = As + bi * 8192;
        const _Float16* Bb = Bs + bi * 8192;
        const int r16 = lane & 15;
        #pragma unroll
        for (int kh = 0; kh < 2; ++kh) {
            const int ks = (lane >> 4) + kh * 4;
            half8_t a[4], b[2];
            #pragma unroll
            for (int mi = 0; mi < 4; ++mi) {
                int row = wr + mi * 16 + r16;
                a[mi] = *(const half8_t*)(Ab + row * 64 + ((ks ^ (row & 7)) * 8));
            }
            #pragma unroll
            for (int ni = 0; ni < 2; ++ni) {
                int col = wc + ni * 16 + r16;
                b[ni] = *(const half8_t*)(Bb + col * 64 + ((ks ^ (col & 7)) * 8));
            }
            #pragma unroll
            for (int mi = 0; mi < 4; ++mi)
                #pragma unroll
                for (int ni = 0; ni < 2; ++ni)
                    acc[mi][ni] = __builtin_amdgcn_mfma_f32_16x16x32_f16(
                        a[mi], b[ni], acc[mi][ni], 0, 0, 0);
        }
    };

    if constexpr (DEPTH == 3) {
        stage(0, 0);
        stage(1, 1);
        int buf = 0;
        #pragma unroll 1
        for (int kt = 0; kt < NKT - 1; ++kt) {
            asm volatile("s_waitcnt vmcnt(4)" ::: "memory");
            __builtin_amdgcn_s_barrier();
            if (kt + 2 < NKT) {
                int bi2 = buf + 2; if (bi2 >= 3) bi2 -= 3;
                stage(kt + 2, bi2);
            }
            compute(buf);
            ++buf; if (buf == 3) buf = 0;
        }
        asm volatile("s_waitcnt vmcnt(0)" ::: "memory");
        __builtin_amdgcn_s_barrier();
        compute(buf);
    } else {
        stage(0, 0);
        int buf = 0;
        #pragma unroll 1
        for (int kt = 0; kt < NKT; ++kt) {
            __syncthreads();                  // drains vmcnt(0) + barrier
            if (kt + 1 < NKT) stage(kt + 1, buf ^ 1);
            compute(buf);
            buf ^= 1;
        }
    }

    // C/D layout: col = lane&15, row = (lane>>4)*4 + q
    if constexpr (EPI == 0 || EPI == 2) {
        float* out = (float*)outv;
        #pragma unroll
        for (int mi = 0; mi < 4; ++mi) {
            int r = row0 + wr + mi * 16 + (lane >> 4) * 4;
            #pragma unroll
            for (int ni = 0; ni < 2; ++ni) {
                int cidx = col0 + wc + ni * 16 + (lane & 15);
                float bv = (EPI == 0) ? bias[cidx] : 0.f;
                #pragma unroll
                for (int q = 0; q < 4; ++q)
                    out[(size_t)(r + q) * HID + cidx] = acc[mi][ni][q] + bv;
            }
        }
    } else {
        // transposed f16 scatter: YT[b][o0+c][t*256 + m0 + r]
        __syncthreads();                       // all compute reads done; reuse smem
        _Float16* ep = smem;                   // [128 c][136]
        #pragma unroll
        for (int mi = 0; mi < 4; ++mi) {
            int rb = wr + mi * 16 + (lane >> 4) * 4;
            #pragma unroll
            for (int ni = 0; ni < 2; ++ni) {
                int c = wc + ni * 16 + (lane & 15);
                half4_t h4;
                #pragma unroll
                for (int q = 0; q < 4; ++q) h4[q] = (_Float16)acc[mi][ni][q];
                *(half4_t*)&ep[c * 136 + rb] = h4;
            }
        }
        __syncthreads();
        const int b = row0 >> 8, m0 = row0 & 255, t = col0 >> 9, o0 = col0 & 511;
        _Float16* yb = (_Float16*)outv + ((size_t)b * 512 + o0) * 768 + (size_t)t * 256 + m0;
        #pragma unroll
        for (int it = 0; it < 4; ++it) {
            int g = it * 512 + tid;
            int c = g >> 4, m8 = g & 15;
            *(half8_t*)(yb + (size_t)c * 768 + m8 * 8) =
                *(const half8_t*)&ep[c * 136 + m8 * 8];
        }
    }
}

// ------------- LayerNorm + exact GELU: read f32, write f16 row-major -------------
__global__ __launch_bounds__(256) void ln_gelu_f16(const float* __restrict__ h,
    const float* __restrict__ g, const float* __restrict__ bb,
    _Float16* __restrict__ xrm)
{
    int row = blockIdx.x;
    int tid = threadIdx.x;
    float v0 = h[row*512 + tid];
    float v1 = h[row*512 + 256 + tid];
    __shared__ float red[4];
    int wid = tid >> 6, lane = tid & 63;

    float s = v0 + v1;
    #pragma unroll
    for (int off = 32; off; off >>= 1) s += __shfl_down(s, off);
    if (lane == 0) red[wid] = s;
    __syncthreads();
    float mu = (red[0]+red[1]+red[2]+red[3]) * (1.f/512.f);
    __syncthreads();

    float d0 = v0 - mu, d1 = v1 - mu;
    float q = d0*d0 + d1*d1;
    #pragma unroll
    for (int off = 32; off; off >>= 1) q += __shfl_down(q, off);
    if (lane == 0) red[wid] = q;
    __syncthreads();
    float var = (red[0]+red[1]+red[2]+red[3]) * (1.f/512.f);
    float rs = rsqrtf(var + 1e-5f);

    float y0 = d0*rs*g[tid] + bb[tid];
    float y1 = d1*rs*g[tid+256] + bb[tid+256];
    y0 = 0.5f*y0*(1.f + erff(y0*0.70710678118654752f));
    y1 = 0.5f*y1*(1.f + erff(y1*0.70710678118654752f));
    xrm[(size_t)row*512 + tid]       = (_Float16)y0;
    xrm[(size_t)row*512 + 256 + tid] = (_Float16)y1;
}

extern "C" void kernel_launch(void* const* d_in, const int* in_sizes, int n_in,
                              void* d_out, int out_size, void* d_ws, size_t ws_size,
                              hipStream_t stream)
{
    const float* cols   = (const float*)d_in[0];
    const float* logits = (const float*)d_in[1];
    const int*   adj    = (const int*)  d_in[2];
    const float* Wp     = (const float*)d_in[3];
    const float* bp     = (const float*)d_in[4];
    const float* lg     = (const float*)d_in[5];
    const float* lb     = (const float*)d_in[6];
    const float* W      = (const float*)d_in[7];
    const float* V      = (const float*)d_in[8];
    float* out  = (float*)d_out;

    float* xbuf = (float*)d_ws;                                       // 16.8 MB
    char* p = (char*)d_ws + (size_t)ROWS*HID*4;
    _Float16* Acat = (_Float16*)p;  p += (size_t)ROWS*KP*2;           // 9.4 MB
    _Float16* WpT  = (_Float16*)p;  p += (size_t)HID*KP*2;            // 0.6 MB
    _Float16* WcT  = (_Float16*)p;  p += (size_t)1536*HID*2;          // 1.6 MB
    _Float16* C16b = (_Float16*)p;  p += (size_t)ROWS*768*2;          // 12.6 MB
    _Float16* YTb  = (_Float16*)p;  p += (size_t)BSZ*HID*768*2;       // 25.2 MB
    _Float16* Xrm  = Acat;   // reuse: Acat dead after proj GEMM (8.4 <= 9.4 MB)

    prep<<<8584, 256, 0, stream>>>(cols, logits, Wp, W, adj, V, Acat, WpT, WcT, C16b);
    gemm512<KP, 9, 3, 256, 4, 0><<<256, 512, 0, stream>>>(Acat, WpT, bp, xbuf);
    ln_gelu_f16<<<ROWS, 256, 0, stream>>>(xbuf, lg, lb, Xrm);
    gemm512<512, 8, 2, 768, 12, 1><<<768, 512, 0, stream>>>(Xrm, WcT, nullptr, YTb);
    gemm512<768, 12, 3, 256, 4, 2><<<256, 512, 0, stream>>>(C16b, YTb, nullptr, out);
}

// Round 8
// 78.364 us; speedup vs baseline: 4.7852x; 1.0687x over previous
//
#include <hip/hip_runtime.h>
#include <math.h>

#define HID 512
#define NSEQ 256
#define BSZ 32
#define ROWS (BSZ*NSEQ)   // 8192
#define KP 576            // padded proj K (514 -> 576 = 9*64)

typedef _Float16 half8_t __attribute__((ext_vector_type(8)));
typedef _Float16 half4_t __attribute__((ext_vector_type(4)));
typedef float f32x4 __attribute__((ext_vector_type(4)));

__device__ __forceinline__ void gload16(const _Float16* g, _Float16* l) {
    __builtin_amdgcn_global_load_lds(
        (const __attribute__((address_space(1))) unsigned int*)g,
        (__attribute__((address_space(3))) unsigned int*)l, 16, 0, 0);
}

// =============== fused prep: cat_inp | WcT transpose | WpT transpose | buildC ========
// WcT[c][h]  = f16(W[h*1536 + c])            c = t*512+o   [1536][512]
// WpT[o][k]  = f16(Wp[k][o]) zero-pad k>=514                [512][576]
// C16b[(b*256+n)][t*256+m] = f16( lut[adj[b,n,m]][t] + (n==m)*V[0][t] )
__global__ __launch_bounds__(256) void prep(
    const float* __restrict__ cols, const float* __restrict__ logits,
    const float* __restrict__ Wp, const float* __restrict__ W,
    const int* __restrict__ adj, const float* __restrict__ V,
    _Float16* __restrict__ Acat, _Float16* __restrict__ WpT,
    _Float16* __restrict__ WcT, _Float16* __restrict__ C16b)
{
    __shared__ _Float16 ts[64][68];
    __shared__ float lut[16][3];
    __shared__ float V0s[3];
    const int blk = blockIdx.x, tid = threadIdx.x;

    if (blk < 1024) {                       // ---- Acat: concat+cast, 8 rows/block
        int row0 = blk * 8;
        #pragma unroll
        for (int rr = 0; rr < 8; ++rr) {
            int row = row0 + rr;
            for (int k = tid; k < KP; k += 256) {
                float v = 0.f;
                if (k < 512) v = cols[(size_t)row*512 + k];
                else if (k < 514) v = logits[(size_t)row*2 + (k-512)];
                Acat[(size_t)row*KP + k] = (_Float16)v;
            }
        }
    } else if (blk < 1216) {                // ---- WcT (192 blocks: 24 c-tiles x 8 h-tiles)
        int sub = blk - 1024;
        int c0 = (sub % 24) * 64, h0 = (sub / 24) * 64;
        int r = tid >> 2, q = tid & 3;
        #pragma unroll
        for (int i = 0; i < 4; ++i) {
            float4 v = *(const float4*)&W[(size_t)(h0+r)*1536 + c0 + q*16 + i*4];
            ts[r][q*16+i*4+0] = (_Float16)v.x;
            ts[r][q*16+i*4+1] = (_Float16)v.y;
            ts[r][q*16+i*4+2] = (_Float16)v.z;
            ts[r][q*16+i*4+3] = (_Float16)v.w;
        }
        __syncthreads();
        _Float16* op = WcT + (size_t)(c0 + r)*512 + h0 + q*16;
        #pragma unroll
        for (int i = 0; i < 4; ++i) {
            half4_t o;
            #pragma unroll
            for (int j = 0; j < 4; ++j) o[j] = ts[q*16+i*4+j][r];
            *(half4_t*)(op + i*4) = o;
        }
    } else if (blk < 1288) {                // ---- WpT (72 blocks: 9 k-tiles x 8 o-tiles)
        int sub = blk - 1216;
        int k0 = (sub % 9) * 64, o0 = (sub / 9) * 64;
        int r = tid >> 2, q = tid & 3;
        int k = k0 + r;
        #pragma unroll
        for (int i = 0; i < 4; ++i) {
            float4 v = make_float4(0.f,0.f,0.f,0.f);
            if (k < 514) v = *(const float4*)&Wp[(size_t)k*HID + o0 + q*16 + i*4];
            ts[r][q*16+i*4+0] = (_Float16)v.x;
            ts[r][q*16+i*4+1] = (_Float16)v.y;
            ts[r][q*16+i*4+2] = (_Float16)v.z;
            ts[r][q*16+i*4+3] = (_Float16)v.w;
        }
        __syncthreads();
        _Float16* op = WpT + (size_t)(o0 + r)*KP + k0 + q*16;
        #pragma unroll
        for (int i = 0; i < 4; ++i) {
            half4_t o;
            #pragma unroll
            for (int j = 0; j < 4; ++j) o[j] = ts[q*16+i*4+j][r];
            *(half4_t*)(op + i*4) = o;
        }
    } else {                                // ---- C16b (128 blocks: 32 b x 4 n-tiles)
        if (tid < 48) { int r = tid/3, c = tid - r*3; lut[r][c] = (r >= 1) ? V[tid] : 0.f; }
        if (tid < 3) V0s[tid] = V[tid];
        __syncthreads();
        int sub = blk - 1288;
        int b = sub >> 2, nt = sub & 3;
        int n = nt*64 + (tid >> 2), mq = tid & 3;
        const int* ap = adj + ((size_t)(b*NSEQ + n))*NSEQ + mq*64;
        size_t ob = ((size_t)(b*NSEQ + n))*768 + mq*64;
        #pragma unroll
        for (int i = 0; i < 16; ++i) {
            int4 a4 = *(const int4*)(ap + i*4);
            int av[4] = { a4.x, a4.y, a4.z, a4.w };
            #pragma unroll
            for (int t = 0; t < 3; ++t) {
                half4_t o;
                #pragma unroll
                for (int j = 0; j < 4; ++j) {
                    int m = mq*64 + i*4 + j;
                    float v = lut[av[j]][t] + ((m == n) ? V0s[t] : 0.f);
                    o[j] = (_Float16)v;
                }
                *(half4_t*)(C16b + ob + (size_t)t*256 + i*4) = o;
            }
        }
    }
}

// ====== unified 128x128 f16 MFMA GEMM, 512 thr / 8 waves (wave tile 64x32) ======
// A[M][KS], B[.][KS]. EPI: 0 = f32 out[r][512]+bias (proj)
//                          1 = f16 transposed scatter -> YT[b][o][t*256+m] (Y-GEMM)
//                          2 = f32 out[r][512], B base per b = row0>>8 (agg-out)
// DEPTH-deep stage-after-free pipeline, counted vmcnt(4*(DEPTH-1)) in steady
// state; tail peels DEPTH-1 iterations with decreasing waits (vmcnt(4), vmcnt(0)).
template<int KS, int NKT, int DEPTH, int NB, int NBLK, int EPI>
__global__ __launch_bounds__(512) void gemm512(
    const _Float16* __restrict__ A, const _Float16* __restrict__ Bm,
    const float* __restrict__ bias, void* __restrict__ outv)
{
    __shared__ _Float16 smem[DEPTH * 2 * 8192];
    _Float16* As = smem;
    _Float16* Bs = smem + DEPTH * 8192;
    const int tid = threadIdx.x;
    const int w = tid >> 6, lane = tid & 63;
    // XCD-chunked swizzle (NB % 8 == 0)
    const int ell = blockIdx.x;
    const int s = (ell & 7) * (NB / 8) + (ell >> 3);
    const int row0 = (s / NBLK) * 128, col0 = (s % NBLK) * 128;
    const int wr = (w >> 2) * 64, wc = (w & 3) * 32;
    const _Float16* Ag = A + (size_t)row0 * KS;
    const _Float16* Bg = (EPI == 2)
        ? Bm + (size_t)(row0 >> 8) * 512 * KS + (size_t)col0 * KS
        : Bm + (size_t)col0 * KS;

    f32x4 acc[4][2] = {};

    // stage tile kt into buffer bi. LDS dest linear; global source pre-swizzled:
    // physical granule (row, c) holds logical (row, c ^ (row&7)).
    auto stage = [&](int kt, int bi) {
        const _Float16* ga = Ag + kt * 64;
        const _Float16* gb = Bg + kt * 64;
        _Float16* la = As + bi * 8192;
        _Float16* lb = Bs + bi * 8192;
        #pragma unroll
        for (int l = 0; l < 2; ++l) {
            int gw = w * 128 + l * 64;
            int g  = gw + lane;
            int row = g >> 3;
            int c   = (g & 7) ^ (row & 7);
            gload16(ga + (size_t)row * KS + c * 8, la + gw * 8);
        }
        #pragma unroll
        for (int l = 0; l < 2; ++l) {
            int gw = w * 128 + l * 64;
            int g  = gw + lane;
            int row = g >> 3;
            int c   = (g & 7) ^ (row & 7);
            gload16(gb + (size_t)row * KS + c * 8, lb + gw * 8);
        }
    };

    auto compute = [&](int bi) {
        const _Float16* Ab = As + bi * 8192;
        const _Float16* Bb = Bs + bi * 8192;
        const int r16 = lane & 15;
        #pragma unroll
        for (int kh = 0; kh < 2; ++kh) {
            const int ks = (lane >> 4) + kh * 4;
            half8_t a[4], b[2];
            #pragma unroll
            for (int mi = 0; mi < 4; ++mi) {
                int row = wr + mi * 16 + r16;
                a[mi] = *(const half8_t*)(Ab + row * 64 + ((ks ^ (row & 7)) * 8));
            }
            #pragma unroll
            for (int ni = 0; ni < 2; ++ni) {
                int col = wc + ni * 16 + r16;
                b[ni] = *(const half8_t*)(Bb + col * 64 + ((ks ^ (col & 7)) * 8));
            }
            #pragma unroll
            for (int mi = 0; mi < 4; ++mi)
                #pragma unroll
                for (int ni = 0; ni < 2; ++ni)
                    acc[mi][ni] = __builtin_amdgcn_mfma_f32_16x16x32_f16(
                        a[mi], b[ni], acc[mi][ni], 0, 0, 0);
        }
    };

    // prologue: fill all DEPTH buffers (4*DEPTH loads in flight per wave)
    #pragma unroll
    for (int i = 0; i < DEPTH; ++i) stage(i, i);

    int buf = 0;
    // steady state: tiles kt..kt+DEPTH-1 outstanding at loop head; counted wait
    // retires exactly tile kt. Never drains to 0.
    #pragma unroll 1
    for (int kt = 0; kt < NKT - (DEPTH - 1); ++kt) {
        if constexpr (DEPTH == 2) asm volatile("s_waitcnt vmcnt(4)" ::: "memory");
        else                      asm volatile("s_waitcnt vmcnt(8)" ::: "memory");
        __builtin_amdgcn_s_barrier();          // all waves: tile kt resident
        __builtin_amdgcn_s_setprio(1);
        compute(buf);
        __builtin_amdgcn_s_setprio(0);
        asm volatile("" ::: "memory");
        __builtin_amdgcn_s_barrier();          // all waves done reading buf
        if (kt + DEPTH < NKT) stage(kt + DEPTH, buf);
        ++buf; if (buf == DEPTH) buf = 0;
    }
    // tail: DEPTH-1 remaining tiles, decreasing counted waits (drain correctly)
    if constexpr (DEPTH == 3) {
        asm volatile("s_waitcnt vmcnt(4)" ::: "memory");
        __builtin_amdgcn_s_barrier();
        __builtin_amdgcn_s_setprio(1);
        compute(buf);
        __builtin_amdgcn_s_setprio(0);
        asm volatile("" ::: "memory");
        __builtin_amdgcn_s_barrier();
        ++buf; if (buf == DEPTH) buf = 0;
    }
    asm volatile("s_waitcnt vmcnt(0)" ::: "memory");
    __builtin_amdgcn_s_barrier();
    compute(buf);

    // C/D layout: col = lane&15, row = (lane>>4)*4 + q
    if constexpr (EPI == 0 || EPI == 2) {
        float* out = (float*)outv;
        #pragma unroll
        for (int mi = 0; mi < 4; ++mi) {
            int r = row0 + wr + mi * 16 + (lane >> 4) * 4;
            #pragma unroll
            for (int ni = 0; ni < 2; ++ni) {
                int cidx = col0 + wc + ni * 16 + (lane & 15);
                float bv = (EPI == 0) ? bias[cidx] : 0.f;
                #pragma unroll
                for (int q = 0; q < 4; ++q)
                    out[(size_t)(r + q) * HID + cidx] = acc[mi][ni][q] + bv;
            }
        }
    } else {
        // transposed f16 scatter: YT[b][o0+c][t*256 + m0 + r]
        __syncthreads();                       // all compute done; reuse smem
        _Float16* ep = smem;                   // [128 c][136]
        #pragma unroll
        for (int mi = 0; mi < 4; ++mi) {
            int rb = wr + mi * 16 + (lane >> 4) * 4;
            #pragma unroll
            for (int ni = 0; ni < 2; ++ni) {
                int c = wc + ni * 16 + (lane & 15);
                half4_t h4;
                #pragma unroll
                for (int q = 0; q < 4; ++q) h4[q] = (_Float16)acc[mi][ni][q];
                *(half4_t*)&ep[c * 136 + rb] = h4;
            }
        }
        __syncthreads();
        const int b = row0 >> 8, m0 = row0 & 255, t = col0 >> 9, o0 = col0 & 511;
        _Float16* yb = (_Float16*)outv + ((size_t)b * 512 + o0) * 768 + (size_t)t * 256 + m0;
        #pragma unroll
        for (int it = 0; it < 4; ++it) {
            int g = it * 512 + tid;
            int c = g >> 4, m8 = g & 15;
            *(half8_t*)(yb + (size_t)c * 768 + m8 * 8) =
                *(const half8_t*)&ep[c * 136 + m8 * 8];
        }
    }
}

// ------------- LayerNorm + exact GELU: read f32, write f16 row-major -------------
__global__ __launch_bounds__(256) void ln_gelu_f16(const float* __restrict__ h,
    const float* __restrict__ g, const float* __restrict__ bb,
    _Float16* __restrict__ xrm)
{
    int row = blockIdx.x;
    int tid = threadIdx.x;
    float v0 = h[row*512 + tid];
    float v1 = h[row*512 + 256 + tid];
    __shared__ float red[4];
    int wid = tid >> 6, lane = tid & 63;

    float s = v0 + v1;
    #pragma unroll
    for (int off = 32; off; off >>= 1) s += __shfl_down(s, off);
    if (lane == 0) red[wid] = s;
    __syncthreads();
    float mu = (red[0]+red[1]+red[2]+red[3]) * (1.f/512.f);
    __syncthreads();

    float d0 = v0 - mu, d1 = v1 - mu;
    float q = d0*d0 + d1*d1;
    #pragma unroll
    for (int off = 32; off; off >>= 1) q += __shfl_down(q, off);
    if (lane == 0) red[wid] = q;
    __syncthreads();
    float var = (red[0]+red[1]+red[2]+red[3]) * (1.f/512.f);
    float rs = rsqrtf(var + 1e-5f);

    float y0 = d0*rs*g[tid] + bb[tid];
    float y1 = d1*rs*g[tid+256] + bb[tid+256];
    y0 = 0.5f*y0*(1.f + erff(y0*0.70710678118654752f));
    y1 = 0.5f*y1*(1.f + erff(y1*0.70710678118654752f));
    xrm[(size_t)row*512 + tid]       = (_Float16)y0;
    xrm[(size_t)row*512 + 256 + tid] = (_Float16)y1;
}

extern "C" void kernel_launch(void* const* d_in, const int* in_sizes, int n_in,
                              void* d_out, int out_size, void* d_ws, size_t ws_size,
                              hipStream_t stream)
{
    const float* cols   = (const float*)d_in[0];
    const float* logits = (const float*)d_in[1];
    const int*   adj    = (const int*)  d_in[2];
    const float* Wp     = (const float*)d_in[3];
    const float* bp     = (const float*)d_in[4];
    const float* lg     = (const float*)d_in[5];
    const float* lb     = (const float*)d_in[6];
    const float* W      = (const float*)d_in[7];
    const float* V      = (const float*)d_in[8];
    float* out  = (float*)d_out;

    float* xbuf = (float*)d_ws;                                       // 16.8 MB
    char* p = (char*)d_ws + (size_t)ROWS*HID*4;
    _Float16* Acat = (_Float16*)p;  p += (size_t)ROWS*KP*2;           // 9.4 MB
    _Float16* WpT  = (_Float16*)p;  p += (size_t)HID*KP*2;            // 0.6 MB
    _Float16* WcT  = (_Float16*)p;  p += (size_t)1536*HID*2;          // 1.6 MB
    _Float16* C16b = (_Float16*)p;  p += (size_t)ROWS*768*2;          // 12.6 MB
    _Float16* YTb  = (_Float16*)p;  p += (size_t)BSZ*HID*768*2;       // 25.2 MB
    _Float16* Xrm  = Acat;   // reuse: Acat dead after proj GEMM (8.4 <= 9.4 MB)

    prep<<<1416, 256, 0, stream>>>(cols, logits, Wp, W, adj, V, Acat, WpT, WcT, C16b);
    gemm512<KP, 9, 3, 256, 4, 0><<<256, 512, 0, stream>>>(Acat, WpT, bp, xbuf);
    ln_gelu_f16<<<ROWS, 256, 0, stream>>>(xbuf, lg, lb, Xrm);
    gemm512<512, 8, 2, 768, 12, 1><<<768, 512, 0, stream>>>(Xrm, WcT, nullptr, YTb);
    gemm512<768, 12, 3, 256, 4, 2><<<256, 512, 0, stream>>>(C16b, YTb, nullptr, out);
}

// Round 9
// 67.869 us; speedup vs baseline: 5.5252x; 1.1546x over previous
//
#include <hip/hip_runtime.h>
#include <math.h>

#define HID 512
#define NSEQ 256
#define BSZ 32
#define ROWS (BSZ*NSEQ)   // 8192
#define KP 576            // padded proj K (514 -> 576 = 9*64)

typedef _Float16 half8_t __attribute__((ext_vector_type(8)));
typedef _Float16 half4_t __attribute__((ext_vector_type(4)));
typedef float f32x4 __attribute__((ext_vector_type(4)));

__device__ __forceinline__ void gload16(const _Float16* g, _Float16* l) {
    __builtin_amdgcn_global_load_lds(
        (const __attribute__((address_space(1))) unsigned int*)g,
        (__attribute__((address_space(3))) unsigned int*)l, 16, 0, 0);
}

// =============== fused prep: cat_inp | WcT transpose | WpT transpose | buildC ========
// WcT[c][h]  = f16(W[h*1536 + c])            c = t*512+o   [1536][512]
// WpT[o][k]  = f16(Wp[k][o]) zero-pad k>=514                [512][576]
// C16b[(b*256+n)][t*256+m] = f16( lut[adj[b,n,m]][t] + (n==m)*V[0][t] )
__global__ __launch_bounds__(256) void prep(
    const float* __restrict__ cols, const float* __restrict__ logits,
    const float* __restrict__ Wp, const float* __restrict__ W,
    const int* __restrict__ adj, const float* __restrict__ V,
    _Float16* __restrict__ Acat, _Float16* __restrict__ WpT,
    _Float16* __restrict__ WcT, _Float16* __restrict__ C16b)
{
    __shared__ _Float16 ts[64][68];
    __shared__ _Float16 lutH[48];       // [r][t], r=0 zeroed
    __shared__ _Float16 V0h[3];
    const int blk = blockIdx.x, tid = threadIdx.x;

    if (blk < 1024) {                       // ---- Acat: concat+cast, 8 rows/block
        int row0 = blk * 8;
        #pragma unroll
        for (int rr = 0; rr < 8; ++rr) {
            int row = row0 + rr;
            for (int k = tid; k < KP; k += 256) {
                float v = 0.f;
                if (k < 512) v = cols[(size_t)row*512 + k];
                else if (k < 514) v = logits[(size_t)row*2 + (k-512)];
                Acat[(size_t)row*KP + k] = (_Float16)v;
            }
        }
    } else if (blk < 1216) {                // ---- WcT (192 blocks: 24 c-tiles x 8 h-tiles)
        int sub = blk - 1024;
        int c0 = (sub % 24) * 64, h0 = (sub / 24) * 64;
        int r = tid >> 2, q = tid & 3;
        #pragma unroll
        for (int i = 0; i < 4; ++i) {
            float4 v = *(const float4*)&W[(size_t)(h0+r)*1536 + c0 + q*16 + i*4];
            ts[r][q*16+i*4+0] = (_Float16)v.x;
            ts[r][q*16+i*4+1] = (_Float16)v.y;
            ts[r][q*16+i*4+2] = (_Float16)v.z;
            ts[r][q*16+i*4+3] = (_Float16)v.w;
        }
        __syncthreads();
        _Float16* op = WcT + (size_t)(c0 + r)*512 + h0 + q*16;
        #pragma unroll
        for (int i = 0; i < 4; ++i) {
            half4_t o;
            #pragma unroll
            for (int j = 0; j < 4; ++j) o[j] = ts[q*16+i*4+j][r];
            *(half4_t*)(op + i*4) = o;
        }
    } else if (blk < 1288) {                // ---- WpT (72 blocks: 9 k-tiles x 8 o-tiles)
        int sub = blk - 1216;
        int k0 = (sub % 9) * 64, o0 = (sub / 9) * 64;
        int r = tid >> 2, q = tid & 3;
        int k = k0 + r;
        #pragma unroll
        for (int i = 0; i < 4; ++i) {
            float4 v = make_float4(0.f,0.f,0.f,0.f);
            if (k < 514) v = *(const float4*)&Wp[(size_t)k*HID + o0 + q*16 + i*4];
            ts[r][q*16+i*4+0] = (_Float16)v.x;
            ts[r][q*16+i*4+1] = (_Float16)v.y;
            ts[r][q*16+i*4+2] = (_Float16)v.z;
            ts[r][q*16+i*4+3] = (_Float16)v.w;
        }
        __syncthreads();
        _Float16* op = WpT + (size_t)(o0 + r)*KP + k0 + q*16;
        #pragma unroll
        for (int i = 0; i < 4; ++i) {
            half4_t o;
            #pragma unroll
            for (int j = 0; j < 4; ++j) o[j] = ts[q*16+i*4+j][r];
            *(half4_t*)(op + i*4) = o;
        }
    } else {                                // ---- C16b (128 blocks: 32 b x 4 n-tiles)
        if (tid < 48) { int r = tid/3; lutH[tid] = (_Float16)((r >= 1) ? V[tid] : 0.f); }
        if (tid < 3) V0h[tid] = (_Float16)V[tid];
        __syncthreads();
        int sub = blk - 1288;
        int b = sub >> 2, nt = sub & 3;
        int w = tid >> 6, lane = tid & 63;
        // one wave per n-row: lanes cover m = lane*4 -> 512B coalesced bursts
        #pragma unroll
        for (int i = 0; i < 16; ++i) {
            int n = nt*64 + w*16 + i;
            int4 a4 = *(const int4*)(adj + ((size_t)(b*NSEQ + n))*NSEQ + lane*4);
            int av[4] = { a4.x, a4.y, a4.z, a4.w };
            size_t ob = ((size_t)(b*NSEQ + n))*768 + lane*4;
            #pragma unroll
            for (int t = 0; t < 3; ++t) {
                half4_t o;
                #pragma unroll
                for (int j = 0; j < 4; ++j) o[j] = lutH[av[j]*3 + t];
                if ((n >> 2) == lane) o[n & 3] = (_Float16)(o[n & 3] + V0h[t]);
                *(half4_t*)(C16b + ob + (size_t)t*256) = o;
            }
        }
    }
}

// ====== unified 128x128 f16 MFMA GEMM, 512 thr / 8 waves (wave tile 64x32) ======
// A[M][KS], B[.][KS]. EPI: 0 = f16 row-major out[r][512] + bias (proj)
//                          1 = f16 transposed scatter -> YT[b][o][t*256+m] (Y-GEMM)
//                          2 = f32 out[r][512], B base per b = row0>>8 (agg-out)
// DEPTH-deep stage-after-free pipeline, counted vmcnt(4*(DEPTH-1)) in steady
// state; tail peels DEPTH-1 iterations with decreasing waits (vmcnt(4), vmcnt(0)).
template<int KS, int NKT, int DEPTH, int NB, int NBLK, int EPI>
__global__ __launch_bounds__(512) void gemm512(
    const _Float16* __restrict__ A, const _Float16* __restrict__ Bm,
    const float* __restrict__ bias, void* __restrict__ outv)
{
    __shared__ _Float16 smem[DEPTH * 2 * 8192];
    _Float16* As = smem;
    _Float16* Bs = smem + DEPTH * 8192;
    const int tid = threadIdx.x;
    const int w = tid >> 6, lane = tid & 63;
    // XCD-chunked swizzle (NB % 8 == 0)
    const int ell = blockIdx.x;
    const int s = (ell & 7) * (NB / 8) + (ell >> 3);
    const int row0 = (s / NBLK) * 128, col0 = (s % NBLK) * 128;
    const int wr = (w >> 2) * 64, wc = (w & 3) * 32;
    const _Float16* Ag = A + (size_t)row0 * KS;
    const _Float16* Bg = (EPI == 2)
        ? Bm + (size_t)(row0 >> 8) * 512 * KS + (size_t)col0 * KS
        : Bm + (size_t)col0 * KS;

    f32x4 acc[4][2] = {};

    // stage tile kt into buffer bi. LDS dest linear; global source pre-swizzled:
    // physical granule (row, c) holds logical (row, c ^ (row&7)).
    auto stage = [&](int kt, int bi) {
        const _Float16* ga = Ag + kt * 64;
        const _Float16* gb = Bg + kt * 64;
        _Float16* la = As + bi * 8192;
        _Float16* lb = Bs + bi * 8192;
        #pragma unroll
        for (int l = 0; l < 2; ++l) {
            int gw = w * 128 + l * 64;
            int g  = gw + lane;
            int row = g >> 3;
            int c   = (g & 7) ^ (row & 7);
            gload16(ga + (size_t)row * KS + c * 8, la + gw * 8);
        }
        #pragma unroll
        for (int l = 0; l < 2; ++l) {
            int gw = w * 128 + l * 64;
            int g  = gw + lane;
            int row = g >> 3;
            int c   = (g & 7) ^ (row & 7);
            gload16(gb + (size_t)row * KS + c * 8, lb + gw * 8);
        }
    };

    auto compute = [&](int bi) {
        const _Float16* Ab = As + bi * 8192;
        const _Float16* Bb = Bs + bi * 8192;
        const int r16 = lane & 15;
        #pragma unroll
        for (int kh = 0; kh < 2; ++kh) {
            const int ks = (lane >> 4) + kh * 4;
            half8_t a[4], b[2];
            #pragma unroll
            for (int mi = 0; mi < 4; ++mi) {
                int row = wr + mi * 16 + r16;
                a[mi] = *(const half8_t*)(Ab + row * 64 + ((ks ^ (row & 7)) * 8));
            }
            #pragma unroll
            for (int ni = 0; ni < 2; ++ni) {
                int col = wc + ni * 16 + r16;
                b[ni] = *(const half8_t*)(Bb + col * 64 + ((ks ^ (col & 7)) * 8));
            }
            #pragma unroll
            for (int mi = 0; mi < 4; ++mi)
                #pragma unroll
                for (int ni = 0; ni < 2; ++ni)
                    acc[mi][ni] = __builtin_amdgcn_mfma_f32_16x16x32_f16(
                        a[mi], b[ni], acc[mi][ni], 0, 0, 0);
        }
    };

    // prologue: fill all DEPTH buffers (4*DEPTH loads in flight per wave)
    #pragma unroll
    for (int i = 0; i < DEPTH; ++i) stage(i, i);

    int buf = 0;
    // steady state: counted wait retires exactly tile kt; never drains to 0.
    #pragma unroll 1
    for (int kt = 0; kt < NKT - (DEPTH - 1); ++kt) {
        if constexpr (DEPTH == 2) asm volatile("s_waitcnt vmcnt(4)" ::: "memory");
        else                      asm volatile("s_waitcnt vmcnt(8)" ::: "memory");
        __builtin_amdgcn_s_barrier();          // all waves: tile kt resident
        __builtin_amdgcn_s_setprio(1);
        compute(buf);
        __builtin_amdgcn_s_setprio(0);
        asm volatile("" ::: "memory");
        __builtin_amdgcn_s_barrier();          // all waves done reading buf
        if (kt + DEPTH < NKT) stage(kt + DEPTH, buf);
        ++buf; if (buf == DEPTH) buf = 0;
    }
    // tail: DEPTH-1 remaining tiles, decreasing counted waits (drain correctly)
    if constexpr (DEPTH == 3) {
        asm volatile("s_waitcnt vmcnt(4)" ::: "memory");
        __builtin_amdgcn_s_barrier();
        __builtin_amdgcn_s_setprio(1);
        compute(buf);
        __builtin_amdgcn_s_setprio(0);
        asm volatile("" ::: "memory");
        __builtin_amdgcn_s_barrier();
        ++buf; if (buf == DEPTH) buf = 0;
    }
    asm volatile("s_waitcnt vmcnt(0)" ::: "memory");
    __builtin_amdgcn_s_barrier();
    compute(buf);

    // C/D layout: col = lane&15, row = (lane>>4)*4 + q
    if constexpr (EPI == 2) {
        float* out = (float*)outv;
        #pragma unroll
        for (int mi = 0; mi < 4; ++mi) {
            int r = row0 + wr + mi * 16 + (lane >> 4) * 4;
            #pragma unroll
            for (int ni = 0; ni < 2; ++ni) {
                int cidx = col0 + wc + ni * 16 + (lane & 15);
                #pragma unroll
                for (int q = 0; q < 4; ++q)
                    out[(size_t)(r + q) * HID + cidx] = acc[mi][ni][q];
            }
        }
    } else if constexpr (EPI == 0) {
        // f16 row-major + bias, LDS-repacked to 256B bursts
        __syncthreads();                       // all compute done; reuse smem
        _Float16* ep = smem;                   // [128 r][136]
        #pragma unroll
        for (int mi = 0; mi < 4; ++mi) {
            int rb = wr + mi * 16 + (lane >> 4) * 4;
            #pragma unroll
            for (int ni = 0; ni < 2; ++ni) {
                int c = wc + ni * 16 + (lane & 15);
                float bv = bias[col0 + c];
                #pragma unroll
                for (int q = 0; q < 4; ++q)
                    ep[(rb + q) * 136 + c] = (_Float16)(acc[mi][ni][q] + bv);
            }
        }
        __syncthreads();
        _Float16* ob = (_Float16*)outv + (size_t)row0 * HID + col0;
        #pragma unroll
        for (int it = 0; it < 4; ++it) {
            int g = it * 512 + tid;
            int r = g >> 4, c8 = g & 15;
            *(half8_t*)(ob + (size_t)r * HID + c8 * 8) =
                *(const half8_t*)&ep[r * 136 + c8 * 8];
        }
    } else {
        // transposed f16 scatter: YT[b][o0+c][t*256 + m0 + r]
        __syncthreads();                       // all compute done; reuse smem
        _Float16* ep = smem;                   // [128 c][136]
        #pragma unroll
        for (int mi = 0; mi < 4; ++mi) {
            int rb = wr + mi * 16 + (lane >> 4) * 4;
            #pragma unroll
            for (int ni = 0; ni < 2; ++ni) {
                int c = wc + ni * 16 + (lane & 15);
                half4_t h4;
                #pragma unroll
                for (int q = 0; q < 4; ++q) h4[q] = (_Float16)acc[mi][ni][q];
                *(half4_t*)&ep[c * 136 + rb] = h4;
            }
        }
        __syncthreads();
        const int b = row0 >> 8, m0 = row0 & 255, t = col0 >> 9, o0 = col0 & 511;
        _Float16* yb = (_Float16*)outv + ((size_t)b * 512 + o0) * 768 + (size_t)t * 256 + m0;
        #pragma unroll
        for (int it = 0; it < 4; ++it) {
            int g = it * 512 + tid;
            int c = g >> 4, m8 = g & 15;
            *(half8_t*)(yb + (size_t)c * 768 + m8 * 8) =
                *(const half8_t*)&ep[c * 136 + m8 * 8];
        }
    }
}

// ------- LayerNorm + exact GELU, IN-PLACE on f16 [row][512] (block = row) -------
__global__ __launch_bounds__(256) void ln_gelu_ip(_Float16* __restrict__ h,
    const float* __restrict__ g, const float* __restrict__ bb)
{
    int row = blockIdx.x;
    int tid = threadIdx.x;
    float v0 = (float)h[(size_t)row*512 + tid];
    float v1 = (float)h[(size_t)row*512 + 256 + tid];
    __shared__ float red[4];
    int wid = tid >> 6, lane = tid & 63;

    float s = v0 + v1;
    #pragma unroll
    for (int off = 32; off; off >>= 1) s += __shfl_down(s, off);
    if (lane == 0) red[wid] = s;
    __syncthreads();
    float mu = (red[0]+red[1]+red[2]+red[3]) * (1.f/512.f);
    __syncthreads();

    float d0 = v0 - mu, d1 = v1 - mu;
    float q = d0*d0 + d1*d1;
    #pragma unroll
    for (int off = 32; off; off >>= 1) q += __shfl_down(q, off);
    if (lane == 0) red[wid] = q;
    __syncthreads();
    float var = (red[0]+red[1]+red[2]+red[3]) * (1.f/512.f);
    float rs = rsqrtf(var + 1e-5f);

    float y0 = d0*rs*g[tid] + bb[tid];
    float y1 = d1*rs*g[tid+256] + bb[tid+256];
    y0 = 0.5f*y0*(1.f + erff(y0*0.70710678118654752f));
    y1 = 0.5f*y1*(1.f + erff(y1*0.70710678118654752f));
    h[(size_t)row*512 + tid]       = (_Float16)y0;
    h[(size_t)row*512 + 256 + tid] = (_Float16)y1;
}

extern "C" void kernel_launch(void* const* d_in, const int* in_sizes, int n_in,
                              void* d_out, int out_size, void* d_ws, size_t ws_size,
                              hipStream_t stream)
{
    const float* cols   = (const float*)d_in[0];
    const float* logits = (const float*)d_in[1];
    const int*   adj    = (const int*)  d_in[2];
    const float* Wp     = (const float*)d_in[3];
    const float* bp     = (const float*)d_in[4];
    const float* lg     = (const float*)d_in[5];
    const float* lb     = (const float*)d_in[6];
    const float* W      = (const float*)d_in[7];
    const float* V      = (const float*)d_in[8];
    float* out  = (float*)d_out;

    char* p = (char*)d_ws;
    _Float16* Xh   = (_Float16*)p;  p += (size_t)ROWS*HID*2;          // 8.4 MB
    _Float16* Acat = (_Float16*)p;  p += (size_t)ROWS*KP*2;           // 9.4 MB
    _Float16* WpT  = (_Float16*)p;  p += (size_t)HID*KP*2;            // 0.6 MB
    _Float16* WcT  = (_Float16*)p;  p += (size_t)1536*HID*2;          // 1.6 MB
    _Float16* C16b = (_Float16*)p;  p += (size_t)ROWS*768*2;          // 12.6 MB
    _Float16* YTb  = (_Float16*)p;  p += (size_t)BSZ*HID*768*2;       // 25.2 MB

    prep<<<1416, 256, 0, stream>>>(cols, logits, Wp, W, adj, V, Acat, WpT, WcT, C16b);
    gemm512<KP, 9, 3, 256, 4, 0><<<256, 512, 0, stream>>>(Acat, WpT, bp, Xh);
    ln_gelu_ip<<<ROWS, 256, 0, stream>>>(Xh, lg, lb);
    gemm512<512, 8, 2, 768, 12, 1><<<768, 512, 0, stream>>>(Xh, WcT, nullptr, YTb);
    gemm512<768, 12, 3, 256, 4, 2><<<256, 512, 0, stream>>>(C16b, YTb, nullptr, out);
}